// Round 14
// baseline (2127.932 us; speedup 1.0000x reference)
//
#include <hip/hip_runtime.h>
#include <cstddef>

typedef _Float16 half8v __attribute__((ext_vector_type(8)));
typedef _Float16 half4v __attribute__((ext_vector_type(4)));
typedef float f32x4 __attribute__((ext_vector_type(4)));

#define MFMA32(A, B, C) __builtin_amdgcn_mfma_f32_16x16x32_f16(A, B, C, 0, 0, 0)
#define MFMA16(A, B, C) __builtin_amdgcn_mfma_f32_16x16x16f16(A, B, C, 0, 0, 0)

// ============ kw2: W2 -> f16 copy ============
__global__ void kw2_kernel(const float* __restrict__ W2, _Float16* __restrict__ w2h) {
  int i = blockIdx.x * 256 + threadIdx.x;
  w2h[i] = (_Float16)W2[i];
}

#define BAR() asm volatile("s_waitcnt lgkmcnt(0)\n\ts_barrier" ::: "memory")

// ============ scan body (round-7 proven; optional flag-gated STAGE from round 9) ============
template <bool PK, bool ZW>
__device__ __forceinline__ void scan_body(
    const int b, const int ct,
    _Float16* __restrict__ svhc, _Float16* __restrict__ hbc,
    float (*__restrict__ h2pc)[320], float (*__restrict__ qppc)[64],
    const float* __restrict__ ug, const float* __restrict__ Kg,
    const float* __restrict__ W1, const float* __restrict__ W2,
    const float* __restrict__ m_init, const float* __restrict__ Qd,
    const float* __restrict__ Q0d, const _Float16* __restrict__ pfb,
    const float* __restrict__ cgp, const _Float16* __restrict__ rfb,
    const _Float16* __restrict__ kab, const float* __restrict__ zpcb,
    const float* __restrict__ klcp, float* __restrict__ out_zf,
    float* __restrict__ out_mf, float* __restrict__ out_kl,
    unsigned* flags) {
  const int wvc = ct >> 6;
  const int ln = ct & 63;
  const int g = ln >> 4;
  const int c = ln & 15;

#define WAITF(T) do { if (flags) { \
    unsigned* fp_ = flags + ((size_t)b * 256 + (size_t)(T)); \
    while (__hip_atomic_load(fp_, __ATOMIC_ACQUIRE, __HIP_MEMORY_SCOPE_AGENT) == 0u) \
      __builtin_amdgcn_s_sleep(8); } } while (0)

  half8v w1f[4][4];
#pragma unroll
  for (int mt = 0; mt < 4; ++mt)
#pragma unroll
    for (int kt = 0; kt < 4; ++kt) {
      half8v v;
#pragma unroll
      for (int j = 0; j < 8; ++j)
        v[j] = (_Float16)W1[(size_t)(kt * 32 + g * 8 + j) * 256 + (wvc * 64 + mt * 16 + c)];
      w1f[mt][kt] = v;
    }
  half8v w2f[2][8];
#pragma unroll
  for (int mt = 0; mt < 2; ++mt)
#pragma unroll
    for (int kt = 0; kt < 8; ++kt) {
      half8v v;
#pragma unroll
      for (int j = 0; j < 8; ++j)
        v[j] = (_Float16)W2[(size_t)(kt * 32 + g * 8 + j) * 128 + (wvc * 32 + mt * 16 + c)];
      w2f[mt][kt] = v;
    }

  f32x4 qiv[2], qiv0[2];
#pragma unroll
  for (int mt = 0; mt < 2; ++mt) {
    f32x4 q = *(const f32x4*)&Qd[wvc * 32 + mt * 16 + g * 4];
    f32x4 q0 = *(const f32x4*)&Q0d[wvc * 32 + mt * 16 + g * 4];
#pragma unroll
    for (int r = 0; r < 4; ++r) { qiv[mt][r] = 1.f / q[r]; qiv0[mt][r] = 1.f / q0[r]; }
  }

  f32x4 zreg[2];

  half8v pfx0, pfx1, kax0 = {}, kax1 = {}, rfa0, rfa1, rfc0, rfc1;
  float kf0[8], kf1[8];
  f32x4 zq0[2], zq1[2], cv0[2], cv1[2];
  f32x4 ur0[2] = {}, ur1[2] = {};
  float kv0 = 0.f, kv1 = 0.f;

  const char* pf_p = (const char*)pfb + (size_t)b * 256 * 4096 + (size_t)ct * 16;
  const char* ka_p = PK ? (const char*)kab + (size_t)b * 256 * 4096 + (size_t)ct * 16
                        : (const char*)pfb;
  const char* K_p = (const char*)Kg + (size_t)b * 256 * 8192 + (size_t)((wvc * 32 + g * 4) * 16 + c) * 4;
  const char* rf_p = (const char*)rfb + (size_t)b * 256 * 8192 + (size_t)ct * 32;
  const char* zq_p = ZW ? (const char*)zpcb + (size_t)b * 256 * 8192 + (size_t)(c * 128 + wvc * 32 + g * 4) * 4
                        : (const char*)out_zf + ((((size_t)c * 64 + b) * 256) * 128 + wvc * 32 + g * 4) * 4;
  const size_t zq_str = ZW ? 8192 : 512;
  const char* cv_p = (const char*)cgp + (size_t)b * 256 * 512 + (size_t)(wvc * 32 + g * 4) * 4;
  const char* ur_p = (const char*)ug + (size_t)b * 256 * 256 + (size_t)(wvc * 32 + g * 4) * 4;
  const char* kl_p = (const char*)klcp + (size_t)b * 256 * 4;
  char* zf_p = (char*)out_zf + ((((size_t)c * 64 + b) * 256) * 128 + wvc * 32 + g * 4) * 4;
  char* mf_p = (char*)out_mf + ((size_t)b * 256 * 128 + wvc * 32 + g * 4) * 4;

#define STAGE(BI) do { \
    pfx##BI = *(const half8v*)pf_p; pf_p += 4096; \
    if constexpr (PK) { kax##BI = *(const half8v*)ka_p; ka_p += 4096; } \
    else { _Pragma("unroll") for (int kt_ = 0; kt_ < 2; ++kt_) \
             _Pragma("unroll") for (int j_ = 0; j_ < 4; ++j_) \
               kf##BI[kt_ * 4 + j_] = *(const float*)(K_p + kt_ * 1024 + j_ * 64); \
           K_p += 8192; } \
    rfa##BI = *(const half8v*)rf_p; rfc##BI = *(const half8v*)(rf_p + 16); rf_p += 8192; \
    zq##BI[0] = *(const f32x4*)zq_p; zq##BI[1] = *(const f32x4*)(zq_p + 64); zq_p += zq_str; \
    cv##BI[0] = *(const f32x4*)cv_p; cv##BI[1] = *(const f32x4*)(cv_p + 64); cv_p += 512; \
    if (wvc < 2) { ur##BI[0] = *(const f32x4*)ur_p; ur##BI[1] = *(const f32x4*)(ur_p + 64); } \
    ur_p += 256; \
    kv##BI = *(const float*)kl_p; kl_p += 4; \
  } while (0)

#define KAH(BI, KT, DST) do { \
    if constexpr (PK) { _Pragma("unroll") for (int j_ = 0; j_ < 4; ++j_) DST[j_] = kax##BI[(KT) * 4 + j_]; } \
    else { _Pragma("unroll") for (int j_ = 0; j_ < 4; ++j_) DST[j_] = (_Float16)kf##BI[(KT) * 4 + j_]; } \
  } while (0)

#define PHASE_A(BI) do { \
    half4v zbh_[2], zbl_[2]; \
    _Pragma("unroll") for (int kt = 0; kt < 2; ++kt) \
      _Pragma("unroll") for (int j = 0; j < 4; ++j) { \
        float x_ = zreg[kt][j]; _Float16 h_ = (_Float16)x_; \
        zbh_[kt][j] = h_; zbl_[kt][j] = (_Float16)(x_ - (float)h_); } \
    half8v zh8_[4]; \
    _Pragma("unroll") for (int kt = 0; kt < 4; ++kt) { \
      int row_ = kt * 4 + g; \
      int idx_ = row_ * 128 + (((c + row_) & 15) << 3); \
      zh8_[kt] = *(const half8v*)&svhc[idx_]; } \
    f32x4 a1h_[4]; \
    _Pragma("unroll") for (int mt = 0; mt < 4; ++mt) a1h_[mt] = (f32x4){0,0,0,0}; \
    _Pragma("unroll") for (int kt = 0; kt < 4; ++kt) \
      _Pragma("unroll") for (int mt = 0; mt < 4; ++mt) \
        a1h_[mt] = MFMA32(w1f[mt][kt], zh8_[kt], a1h_[mt]); \
    half4v th_[4]; \
    _Pragma("unroll") for (int mt = 0; mt < 4; ++mt) { \
      _Pragma("unroll") for (int r = 0; r < 4; ++r) { \
        float x_ = a1h_[mt][r]; \
        float e_ = __expf(2.f * x_); \
        th_[mt][r] = (_Float16)(1.f - 2.f / (e_ + 1.f)); } \
      int row_ = wvc * 8 + mt * 2 + (g >> 1); \
      *(half4v*)&hbc[row_ * 128 + (((c + row_) & 15) << 3) + ((g & 1) << 2)] = th_[mt]; } \
    half4v ka0_, ka1_; KAH(BI, 0, ka0_); KAH(BI, 1, ka1_); \
    f32x4 hz_ = {0, 0, 0, 0}; \
    hz_ = MFMA16(ka0_, zbh_[0], hz_); hz_ = MFMA16(ka1_, zbh_[1], hz_); \
    hz_ = MFMA16(ka0_, zbl_[0], hz_); hz_ = MFMA16(ka1_, zbl_[1], hz_); \
    f32x4 hr_ = {0, 0, 0, 0}; \
    _Pragma("unroll") for (int mt = 0; mt < 4; ++mt) { \
      half4v rr_; \
      _Pragma("unroll") for (int j = 0; j < 4; ++j) \
        rr_[j] = (mt < 2) ? rfa##BI[mt * 4 + j] : rfc##BI[(mt - 2) * 4 + j]; \
      hr_ = MFMA16(rr_, th_[mt], hr_); } \
    *(f32x4*)&h2pc[wvc][c * 20 + g * 4] = hz_ + hr_; \
  } while (0)

#define EPILOG(BI, QIV, MV) do { \
    f32x4 h2v_ = *(const f32x4*)&h2pc[0][c * 20 + g * 4]; \
    h2v_ += *(const f32x4*)&h2pc[1][c * 20 + g * 4]; \
    h2v_ += *(const f32x4*)&h2pc[2][c * 20 + g * 4]; \
    h2v_ += *(const f32x4*)&h2pc[3][c * 20 + g * 4]; \
    half4v h2h_, h2l_; \
    _Pragma("unroll") for (int j = 0; j < 4; ++j) { \
      _Float16 h_ = (_Float16)h2v_[j]; \
      h2h_[j] = h_; h2l_[j] = (_Float16)(h2v_[j] - (float)h_); } \
    float qpl_ = 0.f; \
    _Pragma("unroll") for (int mt = 0; mt < 2; ++mt) { \
      half4v pfm_; \
      _Pragma("unroll") for (int j = 0; j < 4; ++j) pfm_[j] = pfx##BI[mt * 4 + j]; \
      f32x4 zz_ = {0, 0, 0, 0}; \
      f32x4 mh_ = MFMA16(pfm_, h2h_, zz_); \
      f32x4 mlv_ = MFMA16(pfm_, h2l_, zz_); \
      f32x4 dd_ = cv##BI[mt] - (mh_ + mlv_); \
      f32x4 mf_ = MV[mt] + dd_; \
      f32x4 zf_ = mf_ + zq##BI[mt]; \
      _Pragma("unroll") for (int r = 0; r < 4; ++r) qpl_ += dd_[r] * dd_[r] * QIV[mt][r]; \
      *(f32x4*)(zf_p + mt * 64) = zf_; \
      zreg[mt] = zf_; \
      half4v zh4_; \
      _Pragma("unroll") for (int r = 0; r < 4; ++r) zh4_[r] = (_Float16)zf_[r]; \
      int row_ = wvc * 4 + mt * 2 + (g >> 1); \
      int base_ = row_ * 128 + (((c + row_) & 15) << 3) + ((g & 1) << 2); \
      *(half4v*)&svhc[base_] = zh4_; \
      f32x4 ms_ = mf_; \
      _Pragma("unroll") for (int r = 0; r < 4; ++r) { \
        float x_ = ms_[r]; \
        x_ += __shfl_xor(x_, 1); x_ += __shfl_xor(x_, 2); \
        x_ += __shfl_xor(x_, 4); x_ += __shfl_xor(x_, 8); \
        ms_[r] = x_ * 0.0625f; } \
      if (c == 0) *(f32x4*)(mf_p + mt * 64) = ms_; \
    } \
    zf_p += 512; mf_p += 512; \
    qpl_ += __shfl_xor(qpl_, 16); \
    qpl_ += __shfl_xor(qpl_, 32); \
    if (g == 0) qppc[BI][wvc * 16 + c] = qpl_; \
  } while (0)

#define PHASE_B(BI, QIV) do { \
    half8v hf_[8]; \
    _Pragma("unroll") for (int kt = 0; kt < 8; ++kt) { \
      int row_ = kt * 4 + g; \
      hf_[kt] = *(const half8v*)&hbc[row_ * 128 + (((c + row_) & 15) << 3)]; } \
    f32x4 a2a_[2], a2b_[2]; \
    _Pragma("unroll") for (int mt = 0; mt < 2; ++mt) { a2a_[mt] = (f32x4){0,0,0,0}; a2b_[mt] = (f32x4){0,0,0,0}; } \
    _Pragma("unroll") for (int kt = 0; kt < 4; ++kt) \
      _Pragma("unroll") for (int mt = 0; mt < 2; ++mt) { \
        a2a_[mt] = MFMA32(w2f[mt][kt], hf_[kt], a2a_[mt]); \
        a2b_[mt] = MFMA32(w2f[mt][kt + 4], hf_[kt + 4], a2b_[mt]); } \
    f32x4 mv_[2]; \
    _Pragma("unroll") for (int mt = 0; mt < 2; ++mt) { \
      mv_[mt] = zreg[mt] + a2a_[mt] + a2b_[mt]; \
      if (wvc < 2) mv_[mt] += ur##BI[mt]; } \
    EPILOG(BI, QIV, mv_); \
  } while (0)

#define KL_FIN(PBI, TPREV) do { \
    if (ct < 16) { \
      float v_ = qppc[PBI][ct] + qppc[PBI][16 + ct] + qppc[PBI][32 + ct] + qppc[PBI][48 + ct]; \
      v_ += __shfl_xor(v_, 1); v_ += __shfl_xor(v_, 2); \
      v_ += __shfl_xor(v_, 4); v_ += __shfl_xor(v_, 8); \
      if (ct == 0) out_kl[(size_t)b * 256 + (size_t)(TPREV)] = 0.03125f * v_ + kv##PBI; \
    } \
  } while (0)

  // ---------------- t = 0 ----------------
  WAITF(0);
  STAGE(0);
  WAITF(1);
  STAGE(1);
  {
    f32x4 mv0[2];
#pragma unroll
    for (int mt = 0; mt < 2; ++mt) {
      mv0[mt] = *(const f32x4*)&m_init[wvc * 32 + mt * 16 + g * 4];
      if (wvc < 2) mv0[mt] += ur0[mt];
    }
    half4v mh0[2], ml0[2];
#pragma unroll
    for (int kt = 0; kt < 2; ++kt)
#pragma unroll
      for (int j = 0; j < 4; ++j) {
        float x = mv0[kt][j];
        _Float16 h = (_Float16)x;
        mh0[kt][j] = h;
        ml0[kt][j] = (_Float16)(x - (float)h);
      }
    half4v ka0_, ka1_;
    KAH(0, 0, ka0_); KAH(0, 1, ka1_);
    f32x4 hz = {0, 0, 0, 0};
    hz = MFMA16(ka0_, mh0[0], hz); hz = MFMA16(ka1_, mh0[1], hz);
    hz = MFMA16(ka0_, ml0[0], hz); hz = MFMA16(ka1_, ml0[1], hz);
    *(f32x4*)&h2pc[wvc][c * 20 + g * 4] = hz;
    BAR();
    EPILOG(0, qiv0, mv0);
    BAR();
  }

  // ---------------- t = 1..254 (pairs) ----------------
  for (int t = 1; t < 255; t += 2) {
    KL_FIN(0, t - 1);
    WAITF(t + 1);
    STAGE(0);
    PHASE_A(1);
    BAR();
    PHASE_B(1, qiv);
    BAR();
    KL_FIN(1, t);
    WAITF(t + 2);
    STAGE(1);
    PHASE_A(0);
    BAR();
    PHASE_B(0, qiv);
    BAR();
  }
  // ---------------- t = 255 ----------------
  KL_FIN(0, 254);
  PHASE_A(1);
  BAR();
  PHASE_B(1, qiv);
  BAR();
  KL_FIN(1, 255);

#undef STAGE
#undef KAH
#undef PHASE_A
#undef EPILOG
#undef PHASE_B
#undef KL_FIN
#undef WAITF
}

// ============ kc3 body (round-12 proven): noise path + R frags from kab f16 ============
__device__ __forceinline__ void kc3_body(
    const int idx, const int tid, char* __restrict__ raw,
    const _Float16* __restrict__ kab, const float* __restrict__ epsz,
    const float* __restrict__ epsw, const float* __restrict__ Qd,
    const float* __restrict__ Q0d, const float* __restrict__ Ainv,
    const _Float16* __restrict__ w2h, _Float16* __restrict__ rfb,
    float* __restrict__ zpcb, float* __restrict__ out_zp) {
  int t = idx >> 6, b = idx & 63;
  size_t bt = (size_t)b * 256 + t;
  const int wv = tid >> 6, ln = tid & 63, g = ln >> 4, c = ln & 15;
  _Float16 (*Ksh)[18] = (_Float16 (*)[18])raw;               // 4608
  float* sq = (float*)(raw + 4608);                          // 512
  float (*Ai)[16] = (float (*)[16])(raw + 5120);             // 1024
  float (*hh)[17] = (float (*)[17])(raw + 6144);             // 1088
  float (*ww)[17] = (float (*)[17])(raw + 7232);             // 1088
  float (*zp)[132] = (float (*)[132])(raw + 8320);           // 8448
  _Float16 (*Rh)[264] = (_Float16 (*)[264])(raw + 16768);    // 8448
  {
    half8v ko = *(const half8v*)(kab + bt * 2048 + (size_t)tid * 8);
#pragma unroll
    for (int kt = 0; kt < 2; ++kt)
#pragma unroll
      for (int j = 0; j < 4; ++j)
        Ksh[wv * 32 + kt * 16 + g * 4 + j][c] = ko[kt * 4 + j];
  }
  ((float*)Ai)[tid] = Ainv[bt * 256 + tid];
  const float* q = (t == 0) ? Q0d : Qd;
  if (tid < 128) sq[tid] = sqrtf(q[tid]);
  __syncthreads();
  {
    const f32x4* ez4 = (const f32x4*)(epsz + ((size_t)t * 16 * 64) * 128);
    f32x4* ozp4 = (f32x4*)out_zp;
    for (int i = tid; i < 512; i += 256) {
      int s = i >> 5, l4 = i & 31;
      f32x4 e = ez4[((size_t)s * 64 + b) * 32 + l4];
      f32x4 sv = *(const f32x4*)&sq[l4 * 4];
      f32x4 v = e * sv;
      *(f32x4*)&zp[s][l4 * 4] = v;
      ozp4[(((size_t)s * 64 + b) * 256 + t) * 32 + l4] = v;
    }
  }
  {
    half8v kA[4];
#pragma unroll
    for (int kt = 0; kt < 4; ++kt)
#pragma unroll
      for (int j = 0; j < 8; ++j) kA[kt][j] = Ksh[kt * 32 + g * 8 + j][c];
#pragma unroll
    for (int i = 0; i < 4; ++i) {
      int tile = wv * 4 + i;
      f32x4 acc = {0, 0, 0, 0};
#pragma unroll
      for (int kt = 0; kt < 4; ++kt) {
        half8v bf = *(const half8v*)&w2h[(size_t)(tile * 16 + c) * 128 + kt * 32 + g * 8];
        acc = MFMA32(kA[kt], bf, acc);
      }
#pragma unroll
      for (int r = 0; r < 4; ++r) Rh[g * 4 + r][tile * 16 + c] = (_Float16)acc[r];
    }
  }
  __syncthreads();
  {
    int s = tid >> 4, r = tid & 15;
    float acc = epsw[(((size_t)t * 16 + s) * 64 + b) * 16 + r];
    for (int l = 0; l < 128; ++l) acc += (float)Ksh[l][r] * zp[s][l];
    hh[s][r] = acc;
  }
  {
    half8v r0, r1;
#pragma unroll
    for (int mt = 0; mt < 4; ++mt)
#pragma unroll
      for (int j = 0; j < 4; ++j) {
        _Float16 v = Rh[c][wv * 64 + mt * 16 + g * 4 + j];
        if (mt < 2) r0[mt * 4 + j] = v; else r1[(mt - 2) * 4 + j] = v;
      }
    *(half8v*)(rfb + bt * 4096 + (size_t)tid * 16) = r0;
    *(half8v*)(rfb + bt * 4096 + (size_t)tid * 16 + 8) = r1;
  }
  __syncthreads();
  {
    int s = tid >> 4, r = tid & 15;
    float acc = 0.f;
    for (int j = 0; j < 16; ++j) acc += Ai[r][j] * hh[s][j];
    ww[s][r] = acc;
  }
  __syncthreads();
  for (int i = tid; i < 2048; i += 256) {
    int s = i >> 7, l = i & 127;
    float acc = 0.f;
    for (int r = 0; r < 16; ++r) acc += (float)Ksh[l][r] * ww[s][r];
    zpcb[bt * 2048 + i] = zp[s][l] - acc;
  }
}

// ============ standalone kernels ============
template <bool PK, bool ZW>
__launch_bounds__(256, 1)
__global__ void kscan1_kernel(const float* __restrict__ ug, const float* __restrict__ Kg,
                              const float* __restrict__ W1, const float* __restrict__ W2,
                              const float* __restrict__ m_init, const float* __restrict__ Qd,
                              const float* __restrict__ Q0d, const _Float16* __restrict__ pfb,
                              const float* __restrict__ cgp, const _Float16* __restrict__ rfb,
                              const _Float16* __restrict__ kab, const float* __restrict__ zpcb,
                              const float* __restrict__ klcp, float* __restrict__ out_zf,
                              float* __restrict__ out_mf, float* __restrict__ out_kl) {
  __shared__ __align__(16) _Float16 svh[2048];
  __shared__ __align__(16) _Float16 hb[4096];
  __shared__ float h2p[4][320];
  __shared__ float qpp[2][64];
  scan_body<PK, ZW>(blockIdx.x, threadIdx.x, svh, hb, h2p, qpp,
                    ug, Kg, W1, W2, m_init, Qd, Q0d, pfb, cgp, rfb, kab, zpcb, klcp,
                    out_zf, out_mf, out_kl, nullptr);
}

__global__ void kc3_kernel(const _Float16* __restrict__ kab, const float* __restrict__ epsz,
                           const float* __restrict__ epsw, const float* __restrict__ Qd,
                           const float* __restrict__ Q0d, const float* __restrict__ Ainv,
                           const _Float16* __restrict__ w2h, _Float16* __restrict__ rfb,
                           float* __restrict__ zpcb, float* __restrict__ out_zp) {
  __shared__ __align__(16) char raw[25216];
  kc3_body(blockIdx.x, threadIdx.x, raw, kab, epsz, epsw, Qd, Q0d, Ainv, w2h, rfb, zpcb, out_zp);
}

// ============ FUSED: 64 scan blocks + 16384 kc3 worker blocks (t-major) ============
__launch_bounds__(256, 1)
__global__ void fused2_kernel(const float* __restrict__ ug, const float* __restrict__ Kg,
                              const float* __restrict__ W1, const float* __restrict__ W2,
                              const float* __restrict__ m_init, const float* __restrict__ Qd,
                              const float* __restrict__ Q0d, const _Float16* __restrict__ pfb,
                              const float* __restrict__ cgp, _Float16* __restrict__ rfb,
                              const _Float16* __restrict__ kab, float* __restrict__ zpcb,
                              const float* __restrict__ klcp,
                              const float* __restrict__ epsz, const float* __restrict__ epsw,
                              const float* __restrict__ Ainv, const _Float16* __restrict__ w2h,
                              unsigned* __restrict__ flags,
                              float* __restrict__ out_zf, float* __restrict__ out_mf,
                              float* __restrict__ out_zp, float* __restrict__ out_kl) {
  __shared__ __align__(16) char raw[25216];
  const int tid = threadIdx.x;
  if (blockIdx.x < 64) {
    _Float16* svh = (_Float16*)raw;
    _Float16* hb = (_Float16*)(raw + 4096);
    float (*h2p)[320] = (float (*)[320])(raw + 12288);
    float (*qpp)[64] = (float (*)[64])(raw + 17408);
    scan_body<true, true>(blockIdx.x, tid, svh, hb, h2p, qpp,
                          ug, Kg, W1, W2, m_init, Qd, Q0d, pfb, cgp, rfb, kab,
                          zpcb, klcp, out_zf, out_mf, out_kl, flags);
    return;
  }
  const int idx = (int)blockIdx.x - 64;   // t-major: t = idx>>6 ascending with dispatch
  kc3_body(idx, tid, raw, kab, epsz, epsw, Qd, Q0d, Ainv, w2h, rfb, zpcb, out_zp);
  __syncthreads();
  if (tid == 0) {
    int t = idx >> 6, b = idx & 63;
    __threadfence();
    __hip_atomic_store(&flags[(size_t)b * 256 + t], 1u, __ATOMIC_RELEASE,
                       __HIP_MEMORY_SCOPE_AGENT);
  }
}

// ============ kprep1 (round-12 proven): A, chol, Ainv, klc, pf, c', kab ============
__global__ void kprep1_kernel(const float* __restrict__ Kg, const float* __restrict__ kg,
                              const float* __restrict__ ug, const float* __restrict__ Qd,
                              const float* __restrict__ Q0d, float* __restrict__ Ainv,
                              float* __restrict__ klc, _Float16* __restrict__ pfb,
                              float* __restrict__ cgp, _Float16* __restrict__ kab) {
  int tid = threadIdx.x;
  int wv = tid >> 6, ln = tid & 63;
  size_t bt = (size_t)blockIdx.x * 4 + wv;
  int t = (int)(bt & 255);
  __shared__ __align__(16) float Ks[4][128][20];
  __shared__ float qs[4][128];
  __shared__ float vvs[4][128];
  __shared__ float Asm[4][16][20];
  __shared__ float LiL[4][16][20];
  __shared__ float AiS[4][16][20];
  __shared__ float yps[4][4][16];
  __shared__ float yvs[4][16];
  const f32x4* kp4 = (const f32x4*)(Kg + bt * 2048);
  for (int i = ln; i < 512; i += 64) {
    f32x4 v = kp4[i];
    *(f32x4*)&Ks[wv][i >> 2][(i & 3) * 4] = v;
  }
  for (int l = ln; l < 128; l += 64) {
    float q = (t == 0) ? Q0d[l] : Qd[l];
    qs[wv][l] = q;
    float v = Qd[l] * kg[bt * 128 + l];
    if (t > 0 && l < 64) v += ug[bt * 64 + l];
    vvs[wv][l] = v;
  }
  __syncthreads();
  if (kab) {
    int gg = ln >> 4, cc2 = ln & 15;
#pragma unroll
    for (int q = 0; q < 4; ++q) {
      half8v ko;
#pragma unroll
      for (int kt = 0; kt < 2; ++kt)
#pragma unroll
        for (int j = 0; j < 4; ++j)
          ko[kt * 4 + j] = (_Float16)Ks[wv][q * 32 + kt * 16 + gg * 4 + j][cc2];
      *(half8v*)(kab + bt * 2048 + (size_t)(q * 64 + ln) * 8) = ko;
    }
  }
  {
    int r = ln & 15, c0 = (ln >> 4) << 2;
    float a0 = 0, a1 = 0, a2 = 0, a3 = 0;
    for (int l = 0; l < 128; ++l) {
      float kq = Ks[wv][l][r] * qs[wv][l];
      const float* row = &Ks[wv][l][c0];
      a0 += kq * row[0]; a1 += kq * row[1]; a2 += kq * row[2]; a3 += kq * row[3];
    }
    Asm[wv][r][c0 + 0] = a0 + ((r == c0 + 0) ? 1.f : 0.f);
    Asm[wv][r][c0 + 1] = a1 + ((r == c0 + 1) ? 1.f : 0.f);
    Asm[wv][r][c0 + 2] = a2 + ((r == c0 + 2) ? 1.f : 0.f);
    Asm[wv][r][c0 + 3] = a3 + ((r == c0 + 3) ? 1.f : 0.f);
  }
  {
    int r = ln & 15, seg = ln >> 4;
    float s = 0.f;
    for (int l = seg * 32; l < seg * 32 + 32; ++l) s += Ks[wv][l][r] * vvs[wv][l];
    yps[wv][seg][r] = s;
  }
  __syncthreads();
  if (ln < 16) {
    int i = ln;
    float ar[16], Lr[16];
#pragma unroll
    for (int j = 0; j < 16; ++j) ar[j] = Asm[wv][i][j];
    float ld = 0.f;
#pragma unroll
    for (int j = 0; j < 16; ++j) {
      float ajj = __shfl(ar[j], j, 64);
      float d = sqrtf(ajj);
      ld += __logf(d);
      float li = ar[j] / d;
      li = (i >= j) ? li : 0.f;
      Lr[j] = li;
#pragma unroll
      for (int k2 = j; k2 < 16; ++k2) {
        float lk = __shfl(li, k2, 64);
        ar[k2] -= li * lk;
      }
    }
    int cc = i;
    float Lic[16];
#pragma unroll
    for (int ii = 0; ii < 16; ++ii) {
      float s = (ii == cc) ? 1.f : 0.f;
#pragma unroll
      for (int p = 0; p < 16; ++p) {
        if (p < ii) {
          float Lip = __shfl(Lr[p], ii, 64);
          s -= Lip * Lic[p];
        }
      }
      float dii = __shfl(Lr[ii], ii, 64);
      float v = s / dii;
      Lic[ii] = (ii >= cc) ? v : 0.f;
    }
    float tr = 0.f;
#pragma unroll
    for (int ii = 0; ii < 16; ++ii) { tr += Lic[ii] * Lic[ii]; LiL[wv][cc][ii] = Lic[ii]; }
    tr += __shfl_xor(tr, 1); tr += __shfl_xor(tr, 2);
    tr += __shfl_xor(tr, 4); tr += __shfl_xor(tr, 8);
    if (cc == 0) klc[bt] = 0.5f * (tr - 16.f + 2.f * ld);
    yvs[wv][cc] = yps[wv][0][cc] + yps[wv][1][cc] + yps[wv][2][cc] + yps[wv][3][cc];
  }
  __syncthreads();
  {
    int r = ln & 15, c0 = (ln >> 4) << 2;
    float a0 = 0, a1 = 0, a2 = 0, a3 = 0;
    for (int ii = 0; ii < 16; ++ii) {
      float lir = LiL[wv][r][ii];
      a0 += lir * LiL[wv][c0 + 0][ii];
      a1 += lir * LiL[wv][c0 + 1][ii];
      a2 += lir * LiL[wv][c0 + 2][ii];
      a3 += lir * LiL[wv][c0 + 3][ii];
    }
    AiS[wv][r][c0 + 0] = a0; AiS[wv][r][c0 + 1] = a1;
    AiS[wv][r][c0 + 2] = a2; AiS[wv][r][c0 + 3] = a3;
    f32x4 av = {a0, a1, a2, a3};
    *(f32x4*)&Ainv[bt * 256 + r * 16 + c0] = av;
  }
  __syncthreads();
  {
#pragma unroll
    for (int li = 0; li < 2; ++li) {
      int l = ln * 2 + li;
      f32x4 acc0 = {0,0,0,0}, acc1v = {0,0,0,0}, acc2v = {0,0,0,0}, acc3v = {0,0,0,0};
      for (int j = 0; j < 16; ++j) {
        float kj = Ks[wv][l][j];
        acc0  += kj * *(const f32x4*)&AiS[wv][j][0];
        acc1v += kj * *(const f32x4*)&AiS[wv][j][4];
        acc2v += kj * *(const f32x4*)&AiS[wv][j][8];
        acc3v += kj * *(const f32x4*)&AiS[wv][j][12];
      }
      float ql = qs[wv][l];
      float cp = ql * kg[bt * 128 + l];
      float pv[16];
#pragma unroll
      for (int e = 0; e < 4; ++e) {
        pv[e] = ql * acc0[e]; pv[4 + e] = ql * acc1v[e];
        pv[8 + e] = ql * acc2v[e]; pv[12 + e] = ql * acc3v[e];
      }
#pragma unroll
      for (int r = 0; r < 16; ++r) cp -= pv[r] * yvs[wv][r];
      cgp[bt * 128 + l] = cp;
#pragma unroll
      for (int r = 0; r < 16; ++r) Ks[wv][l][r] = pv[r];
    }
  }
  __syncthreads();
  {
    int gp = ln >> 4, cp = ln & 15;
#pragma unroll
    for (int ci = 0; ci < 4; ++ci) {
      half8v o;
#pragma unroll
      for (int mt = 0; mt < 2; ++mt)
#pragma unroll
        for (int j = 0; j < 4; ++j)
          o[mt * 4 + j] = (_Float16)Ks[wv][ci * 32 + mt * 16 + cp][gp * 4 + j];
      *(half8v*)(pfb + bt * 2048 + (size_t)(ci * 64 + ln) * 8) = o;
    }
  }
}

// ============ round-7 small-ws fallback kernels ============
__global__ void kprepR_kernel(const float* __restrict__ Kg, const _Float16* __restrict__ w2h,
                              _Float16* __restrict__ rfb, _Float16* __restrict__ kab) {
  int tid = threadIdx.x;
  int wv = tid >> 6, ln = tid & 63;
  int g = ln >> 4, c = ln & 15;
  __shared__ _Float16 Kh[128][20];
  __shared__ _Float16 Rh[16][264];
  for (int it = 0; it < 4; ++it) {
    size_t bt = (size_t)blockIdx.x * 4 + it;
    const float* kp = Kg + bt * 2048;
    for (int i = tid; i < 2048; i += 256) Kh[i >> 4][i & 15] = (_Float16)kp[i];
    __syncthreads();
    half8v kA[4];
#pragma unroll
    for (int kt = 0; kt < 4; ++kt)
#pragma unroll
      for (int j = 0; j < 8; ++j) kA[kt][j] = Kh[kt * 32 + g * 8 + j][c];
#pragma unroll
    for (int i = 0; i < 4; ++i) {
      int tile = wv * 4 + i;
      f32x4 acc = {0, 0, 0, 0};
#pragma unroll
      for (int kt = 0; kt < 4; ++kt) {
        half8v bf = *(const half8v*)&w2h[(size_t)(tile * 16 + c) * 128 + kt * 32 + g * 8];
        acc = MFMA32(kA[kt], bf, acc);
      }
#pragma unroll
      for (int r = 0; r < 4; ++r) Rh[g * 4 + r][tile * 16 + c] = (_Float16)acc[r];
    }
    __syncthreads();
    half8v r0, r1;
#pragma unroll
    for (int mt = 0; mt < 4; ++mt)
#pragma unroll
      for (int j = 0; j < 4; ++j) {
        _Float16 v = Rh[c][wv * 64 + mt * 16 + g * 4 + j];
        if (mt < 2) r0[mt * 4 + j] = v; else r1[(mt - 2) * 4 + j] = v;
      }
    *(half8v*)(rfb + bt * 4096 + (size_t)tid * 16) = r0;
    *(half8v*)(rfb + bt * 4096 + (size_t)tid * 16 + 8) = r1;
    if (kab) {
      half8v ko;
#pragma unroll
      for (int kt = 0; kt < 2; ++kt)
#pragma unroll
        for (int j = 0; j < 4; ++j) ko[kt * 4 + j] = Kh[wv * 32 + kt * 16 + g * 4 + j][c];
      *(half8v*)(kab + bt * 2048 + (size_t)tid * 8) = ko;
    }
    __syncthreads();
  }
}

__global__ void kc_kernel(const float* __restrict__ Kg, const float* __restrict__ epsz,
                          const float* __restrict__ epsw, const float* __restrict__ Qd,
                          const float* __restrict__ Q0d, const float* __restrict__ Ainv,
                          float* __restrict__ out_zf, float* __restrict__ out_zp,
                          float* __restrict__ zpcb, int zw, int wzp) {
  int idx = blockIdx.x;
  int t = idx >> 6, b = idx & 63;
  int bt = b * 256 + t;
  __shared__ float Ks[128][16];
  __shared__ float Ai[16][16];
  __shared__ float zp[16][129];
  __shared__ float hh[16][17];
  __shared__ float ww[16][17];
  __shared__ float sq[128];
  const float* kp = Kg + (size_t)bt * 2048;
  for (int i = threadIdx.x; i < 2048; i += 256) ((float*)Ks)[i] = kp[i];
  ((float*)Ai)[threadIdx.x] = Ainv[(size_t)bt * 256 + threadIdx.x];
  const float* q = (t == 0) ? Q0d : Qd;
  if (threadIdx.x < 128) sq[threadIdx.x] = sqrtf(q[threadIdx.x]);
  __syncthreads();
  for (int i = threadIdx.x; i < 2048; i += 256) {
    int s = i >> 7, l = i & 127;
    float v = sq[l] * epsz[(((size_t)t * 16 + s) * 64 + b) * 128 + l];
    zp[s][l] = v;
    if (wzp) out_zp[(((size_t)s * 64 + b) * 256 + t) * 128 + l] = v;
  }
  __syncthreads();
  {
    int s = threadIdx.x >> 4, r = threadIdx.x & 15;
    float acc = epsw[(((size_t)t * 16 + s) * 64 + b) * 16 + r];
    for (int l = 0; l < 128; ++l) acc += Ks[l][r] * zp[s][l];
    hh[s][r] = acc;
  }
  __syncthreads();
  {
    int s = threadIdx.x >> 4, r = threadIdx.x & 15;
    float acc = 0.f;
    for (int j = 0; j < 16; ++j) acc += Ai[r][j] * hh[s][j];
    ww[s][r] = acc;
  }
  __syncthreads();
  for (int i = threadIdx.x; i < 2048; i += 256) {
    int s = i >> 7, l = i & 127;
    float acc = 0.f;
    for (int r = 0; r < 16; ++r) acc += Ks[l][r] * ww[s][r];
    float v = zp[s][l] - acc;
    if (zw) zpcb[(size_t)bt * 2048 + i] = v;
    else out_zf[(((size_t)s * 64 + b) * 256 + t) * 128 + l] = v;
  }
}

__global__ void kzp_kernel(const float* __restrict__ epsz, const float* __restrict__ Qd,
                           const float* __restrict__ Q0d, float* __restrict__ out_zp) {
  for (size_t i = (size_t)blockIdx.x * blockDim.x + threadIdx.x; i < (size_t)33554432;
       i += (size_t)gridDim.x * blockDim.x) {
    int l = (int)(i & 127);
    int t = (int)((i >> 7) & 255);
    int sb = (int)(i >> 15);
    int s = sb >> 6, b = sb & 63;
    float q = (t == 0) ? Q0d[l] : Qd[l];
    out_zp[i] = sqrtf(q) * epsz[(((size_t)t * 16 + s) * 64 + b) * 128 + l];
  }
}

extern "C" void kernel_launch(void* const* d_in, const int* in_sizes, int n_in,
                              void* d_out, int out_size, void* d_ws, size_t ws_size,
                              hipStream_t stream) {
  (void)in_sizes; (void)n_in; (void)out_size;
  const float* u   = (const float*)d_in[0];
  const float* kk  = (const float*)d_in[1];
  const float* Kg  = (const float*)d_in[2];
  const float* epz = (const float*)d_in[3];
  const float* epw = (const float*)d_in[4];
  const float* W1  = (const float*)d_in[5];
  const float* W2  = (const float*)d_in[6];
  const float* mi  = (const float*)d_in[7];
  const float* Qd  = (const float*)d_in[8];
  const float* Q0d = (const float*)d_in[9];

  float* out_zf = (float*)d_out;
  float* out_mf = out_zf + (size_t)33554432;
  float* out_zp = out_mf + (size_t)2097152;
  float* out_kl = out_zp + (size_t)33554432;

  char* ws = (char*)d_ws;

  const size_t F_klc  = 0;                 // 65,536
  const size_t F_cgp  = 65536;             // 8,388,608
  const size_t F_pfb  = 8454144;           // 67,108,864
  const size_t F_w2h  = 75563008;          // 65,536
  const size_t F_kab  = 75628544;          // 67,108,864
  const size_t F_rfb  = 142737408;         // 134,217,728
  const size_t F_zpc  = 276955136;         // 134,217,728
  const size_t F_ainv = 411172864;         // 16,777,216
  const size_t F_MID  = 427950080;
  const size_t F_flg  = 427950080;         // 65,536
  const size_t F_END  = 428015616;

  if (ws_size >= F_MID) {
    float*    klc  = (float*)(ws + F_klc);
    float*    cgp  = (float*)(ws + F_cgp);
    _Float16* pfb  = (_Float16*)(ws + F_pfb);
    _Float16* w2h  = (_Float16*)(ws + F_w2h);
    _Float16* kab  = (_Float16*)(ws + F_kab);
    _Float16* rfb  = (_Float16*)(ws + F_rfb);
    float*    zpcb = (float*)(ws + F_zpc);
    float*    Ainv = (float*)(ws + F_ainv);

    bool fuse = ws_size >= F_END;
    if (fuse) {
      hipFuncAttributes fa;
      if (hipFuncGetAttributes(&fa, (const void*)fused2_kernel) != hipSuccess ||
          fa.localSizeBytes != 0)
        fuse = false;
    }

    kw2_kernel<<<128, 256, 0, stream>>>(W2, w2h);
    kprep1_kernel<<<4096, 256, 0, stream>>>(Kg, kk, u, Qd, Q0d, Ainv, klc, pfb, cgp, kab);
    if (fuse) {
      unsigned* flags = (unsigned*)(ws + F_flg);
      (void)hipMemsetAsync(flags, 0, 65536, stream);
      fused2_kernel<<<16448, 256, 0, stream>>>(u, Kg, W1, W2, mi, Qd, Q0d, pfb, cgp,
                                               rfb, kab, zpcb, klc, epz, epw, Ainv, w2h,
                                               flags, out_zf, out_mf, out_zp, out_kl);
    } else {
      kc3_kernel<<<16384, 256, 0, stream>>>(kab, epz, epw, Qd, Q0d, Ainv, w2h,
                                            rfb, zpcb, out_zp);
      kscan1_kernel<true, true><<<64, 256, 0, stream>>>(u, Kg, W1, W2, mi, Qd, Q0d, pfb,
                                                        cgp, rfb, kab, zpcb, klc,
                                                        out_zf, out_mf, out_kl);
    }
    return;
  }

  // ---- small-ws fallback (round-7 path) ----
  size_t off = 0;
  auto take = [&](size_t n) { char* p = ws + off; off += n; return p; };
  float*    Ainv = (float*)take(16777216);
  float*    klc  = (float*)take(65536);
  float*    cgp  = (float*)take(8388608);
  _Float16* pfb  = (_Float16*)take(67108864);
  _Float16* w2h  = (_Float16*)take(65536);
  bool zw = ws_size >= off + 134217728;
  float* zpcb = zw ? (float*)take(134217728) : nullptr;
  bool pk = zw && (ws_size >= off + 67108864);
  _Float16* kab = pk ? (_Float16*)take(67108864) : nullptr;
  bool rfws = ws_size >= off + 134217728;
  _Float16* rfb = rfws ? (_Float16*)take(134217728) : (_Float16*)out_zp;
  int wzp = rfws ? 1 : 0;

  kw2_kernel<<<128, 256, 0, stream>>>(W2, w2h);
  kprep1_kernel<<<4096, 256, 0, stream>>>(Kg, kk, u, Qd, Q0d, Ainv, klc, pfb, cgp, nullptr);
  kprepR_kernel<<<4096, 256, 0, stream>>>(Kg, w2h, rfb, kab);
  kc_kernel<<<16384, 256, 0, stream>>>(Kg, epz, epw, Qd, Q0d, Ainv, out_zf, out_zp,
                                       zpcb, zw ? 1 : 0, wzp);
  if (pk)
    kscan1_kernel<true, true><<<64, 256, 0, stream>>>(u, Kg, W1, W2, mi, Qd, Q0d, pfb, cgp, rfb, kab, zpcb, klc, out_zf, out_mf, out_kl);
  else if (zw)
    kscan1_kernel<false, true><<<64, 256, 0, stream>>>(u, Kg, W1, W2, mi, Qd, Q0d, pfb, cgp, rfb, kab, zpcb, klc, out_zf, out_mf, out_kl);
  else
    kscan1_kernel<false, false><<<64, 256, 0, stream>>>(u, Kg, W1, W2, mi, Qd, Q0d, pfb, cgp, rfb, kab, zpcb, klc, out_zf, out_mf, out_kl);
  if (!rfws) kzp_kernel<<<2048, 256, 0, stream>>>(epz, Qd, Q0d, out_zp);
}

// Round 15
// 1002.369 us; speedup vs baseline: 2.1229x; 2.1229x over previous
//
#include <hip/hip_runtime.h>
#include <cstddef>

typedef _Float16 half8v __attribute__((ext_vector_type(8)));
typedef _Float16 half4v __attribute__((ext_vector_type(4)));
typedef float f32x4 __attribute__((ext_vector_type(4)));

#define MFMA32(A, B, C) __builtin_amdgcn_mfma_f32_16x16x32_f16(A, B, C, 0, 0, 0)
#define MFMA16(A, B, C) __builtin_amdgcn_mfma_f32_16x16x16f16(A, B, C, 0, 0, 0)

// ============ kw2: W2 -> f16 copy ============
__global__ void kw2_kernel(const float* __restrict__ W2, _Float16* __restrict__ w2h) {
  int i = blockIdx.x * 256 + threadIdx.x;
  w2h[i] = (_Float16)W2[i];
}

#define BAR() asm volatile("s_waitcnt lgkmcnt(0)\n\ts_barrier" ::: "memory")

// ============ scan body (round-7 proven) ============
// ZMODE: 0 = zpc aliased in out_zf (f32), 1 = zpcb f32, 2 = zpcb f16 fragments
template <bool PK, int ZMODE>
__device__ __forceinline__ void scan_body(
    const int b, const int ct,
    _Float16* __restrict__ svhc, _Float16* __restrict__ hbc,
    float (*__restrict__ h2pc)[320], float (*__restrict__ qppc)[64],
    const float* __restrict__ ug, const float* __restrict__ Kg,
    const float* __restrict__ W1, const float* __restrict__ W2,
    const float* __restrict__ m_init, const float* __restrict__ Qd,
    const float* __restrict__ Q0d, const _Float16* __restrict__ pfb,
    const float* __restrict__ cgp, const _Float16* __restrict__ rfb,
    const _Float16* __restrict__ kab, const float* __restrict__ zpcb,
    const float* __restrict__ klcp, float* __restrict__ out_zf,
    float* __restrict__ out_mf, float* __restrict__ out_kl) {
  const int wvc = ct >> 6;
  const int ln = ct & 63;
  const int g = ln >> 4;
  const int c = ln & 15;

  half8v w1f[4][4];
#pragma unroll
  for (int mt = 0; mt < 4; ++mt)
#pragma unroll
    for (int kt = 0; kt < 4; ++kt) {
      half8v v;
#pragma unroll
      for (int j = 0; j < 8; ++j)
        v[j] = (_Float16)W1[(size_t)(kt * 32 + g * 8 + j) * 256 + (wvc * 64 + mt * 16 + c)];
      w1f[mt][kt] = v;
    }
  half8v w2f[2][8];
#pragma unroll
  for (int mt = 0; mt < 2; ++mt)
#pragma unroll
    for (int kt = 0; kt < 8; ++kt) {
      half8v v;
#pragma unroll
      for (int j = 0; j < 8; ++j)
        v[j] = (_Float16)W2[(size_t)(kt * 32 + g * 8 + j) * 128 + (wvc * 32 + mt * 16 + c)];
      w2f[mt][kt] = v;
    }

  f32x4 qiv[2], qiv0[2];
#pragma unroll
  for (int mt = 0; mt < 2; ++mt) {
    f32x4 q = *(const f32x4*)&Qd[wvc * 32 + mt * 16 + g * 4];
    f32x4 q0 = *(const f32x4*)&Q0d[wvc * 32 + mt * 16 + g * 4];
#pragma unroll
    for (int r = 0; r < 4; ++r) { qiv[mt][r] = 1.f / q[r]; qiv0[mt][r] = 1.f / q0[r]; }
  }

  f32x4 zreg[2];

  half8v pfx0, pfx1, kax0 = {}, kax1 = {}, rfa0, rfa1, rfc0, rfc1;
  float kf0[8], kf1[8];
  f32x4 zq0[2], zq1[2], cv0[2], cv1[2];
  f32x4 ur0[2] = {}, ur1[2] = {};
  float kv0 = 0.f, kv1 = 0.f;

  const char* pf_p = (const char*)pfb + (size_t)b * 256 * 4096 + (size_t)ct * 16;
  const char* ka_p = PK ? (const char*)kab + (size_t)b * 256 * 4096 + (size_t)ct * 16
                        : (const char*)pfb;
  const char* K_p = (const char*)Kg + (size_t)b * 256 * 8192 + (size_t)((wvc * 32 + g * 4) * 16 + c) * 4;
  const char* rf_p = (const char*)rfb + (size_t)b * 256 * 8192 + (size_t)ct * 32;
  const char* zq_p;
  size_t zq_str;
  if constexpr (ZMODE == 2) {
    zq_p = (const char*)zpcb + (size_t)b * 256 * 4096 + (size_t)ct * 16;
    zq_str = 4096;
  } else if constexpr (ZMODE == 1) {
    zq_p = (const char*)zpcb + (size_t)b * 256 * 8192 + (size_t)(c * 128 + wvc * 32 + g * 4) * 4;
    zq_str = 8192;
  } else {
    zq_p = (const char*)out_zf + ((((size_t)c * 64 + b) * 256) * 128 + wvc * 32 + g * 4) * 4;
    zq_str = 512;
  }
  const char* cv_p = (const char*)cgp + (size_t)b * 256 * 512 + (size_t)(wvc * 32 + g * 4) * 4;
  const char* ur_p = (const char*)ug + (size_t)b * 256 * 256 + (size_t)(wvc * 32 + g * 4) * 4;
  const char* kl_p = (const char*)klcp + (size_t)b * 256 * 4;
  char* zf_p = (char*)out_zf + ((((size_t)c * 64 + b) * 256) * 128 + wvc * 32 + g * 4) * 4;
  char* mf_p = (char*)out_mf + ((size_t)b * 256 * 128 + wvc * 32 + g * 4) * 4;

#define STAGE(BI) do { \
    pfx##BI = *(const half8v*)pf_p; pf_p += 4096; \
    if constexpr (PK) { kax##BI = *(const half8v*)ka_p; ka_p += 4096; } \
    else { _Pragma("unroll") for (int kt_ = 0; kt_ < 2; ++kt_) \
             _Pragma("unroll") for (int j_ = 0; j_ < 4; ++j_) \
               kf##BI[kt_ * 4 + j_] = *(const float*)(K_p + kt_ * 1024 + j_ * 64); \
           K_p += 8192; } \
    rfa##BI = *(const half8v*)rf_p; rfc##BI = *(const half8v*)(rf_p + 16); rf_p += 8192; \
    if constexpr (ZMODE == 2) { \
      half8v zo_ = *(const half8v*)zq_p; \
      _Pragma("unroll") for (int j_ = 0; j_ < 4; ++j_) { \
        zq##BI[0][j_] = (float)zo_[j_]; zq##BI[1][j_] = (float)zo_[4 + j_]; } \
    } else { \
      zq##BI[0] = *(const f32x4*)zq_p; zq##BI[1] = *(const f32x4*)(zq_p + 64); \
    } \
    zq_p += zq_str; \
    cv##BI[0] = *(const f32x4*)cv_p; cv##BI[1] = *(const f32x4*)(cv_p + 64); cv_p += 512; \
    if (wvc < 2) { ur##BI[0] = *(const f32x4*)ur_p; ur##BI[1] = *(const f32x4*)(ur_p + 64); } \
    ur_p += 256; \
    kv##BI = *(const float*)kl_p; kl_p += 4; \
  } while (0)

#define KAH(BI, KT, DST) do { \
    if constexpr (PK) { _Pragma("unroll") for (int j_ = 0; j_ < 4; ++j_) DST[j_] = kax##BI[(KT) * 4 + j_]; } \
    else { _Pragma("unroll") for (int j_ = 0; j_ < 4; ++j_) DST[j_] = (_Float16)kf##BI[(KT) * 4 + j_]; } \
  } while (0)

#define PHASE_A(BI) do { \
    half4v zbh_[2], zbl_[2]; \
    _Pragma("unroll") for (int kt = 0; kt < 2; ++kt) \
      _Pragma("unroll") for (int j = 0; j < 4; ++j) { \
        float x_ = zreg[kt][j]; _Float16 h_ = (_Float16)x_; \
        zbh_[kt][j] = h_; zbl_[kt][j] = (_Float16)(x_ - (float)h_); } \
    half8v zh8_[4]; \
    _Pragma("unroll") for (int kt = 0; kt < 4; ++kt) { \
      int row_ = kt * 4 + g; \
      int idx_ = row_ * 128 + (((c + row_) & 15) << 3); \
      zh8_[kt] = *(const half8v*)&svhc[idx_]; } \
    f32x4 a1h_[4]; \
    _Pragma("unroll") for (int mt = 0; mt < 4; ++mt) a1h_[mt] = (f32x4){0,0,0,0}; \
    _Pragma("unroll") for (int kt = 0; kt < 4; ++kt) \
      _Pragma("unroll") for (int mt = 0; mt < 4; ++mt) \
        a1h_[mt] = MFMA32(w1f[mt][kt], zh8_[kt], a1h_[mt]); \
    half4v th_[4]; \
    _Pragma("unroll") for (int mt = 0; mt < 4; ++mt) { \
      _Pragma("unroll") for (int r = 0; r < 4; ++r) { \
        float x_ = a1h_[mt][r]; \
        float e_ = __expf(2.f * x_); \
        th_[mt][r] = (_Float16)(1.f - 2.f / (e_ + 1.f)); } \
      int row_ = wvc * 8 + mt * 2 + (g >> 1); \
      *(half4v*)&hbc[row_ * 128 + (((c + row_) & 15) << 3) + ((g & 1) << 2)] = th_[mt]; } \
    half4v ka0_, ka1_; KAH(BI, 0, ka0_); KAH(BI, 1, ka1_); \
    f32x4 hz_ = {0, 0, 0, 0}; \
    hz_ = MFMA16(ka0_, zbh_[0], hz_); hz_ = MFMA16(ka1_, zbh_[1], hz_); \
    hz_ = MFMA16(ka0_, zbl_[0], hz_); hz_ = MFMA16(ka1_, zbl_[1], hz_); \
    f32x4 hr_ = {0, 0, 0, 0}; \
    _Pragma("unroll") for (int mt = 0; mt < 4; ++mt) { \
      half4v rr_; \
      _Pragma("unroll") for (int j = 0; j < 4; ++j) \
        rr_[j] = (mt < 2) ? rfa##BI[mt * 4 + j] : rfc##BI[(mt - 2) * 4 + j]; \
      hr_ = MFMA16(rr_, th_[mt], hr_); } \
    *(f32x4*)&h2pc[wvc][c * 20 + g * 4] = hz_ + hr_; \
  } while (0)

#define EPILOG(BI, QIV, MV) do { \
    f32x4 h2v_ = *(const f32x4*)&h2pc[0][c * 20 + g * 4]; \
    h2v_ += *(const f32x4*)&h2pc[1][c * 20 + g * 4]; \
    h2v_ += *(const f32x4*)&h2pc[2][c * 20 + g * 4]; \
    h2v_ += *(const f32x4*)&h2pc[3][c * 20 + g * 4]; \
    half4v h2h_, h2l_; \
    _Pragma("unroll") for (int j = 0; j < 4; ++j) { \
      _Float16 h_ = (_Float16)h2v_[j]; \
      h2h_[j] = h_; h2l_[j] = (_Float16)(h2v_[j] - (float)h_); } \
    float qpl_ = 0.f; \
    _Pragma("unroll") for (int mt = 0; mt < 2; ++mt) { \
      half4v pfm_; \
      _Pragma("unroll") for (int j = 0; j < 4; ++j) pfm_[j] = pfx##BI[mt * 4 + j]; \
      f32x4 zz_ = {0, 0, 0, 0}; \
      f32x4 mh_ = MFMA16(pfm_, h2h_, zz_); \
      f32x4 mlv_ = MFMA16(pfm_, h2l_, zz_); \
      f32x4 dd_ = cv##BI[mt] - (mh_ + mlv_); \
      f32x4 mf_ = MV[mt] + dd_; \
      f32x4 zf_ = mf_ + zq##BI[mt]; \
      _Pragma("unroll") for (int r = 0; r < 4; ++r) qpl_ += dd_[r] * dd_[r] * QIV[mt][r]; \
      *(f32x4*)(zf_p + mt * 64) = zf_; \
      zreg[mt] = zf_; \
      half4v zh4_; \
      _Pragma("unroll") for (int r = 0; r < 4; ++r) zh4_[r] = (_Float16)zf_[r]; \
      int row_ = wvc * 4 + mt * 2 + (g >> 1); \
      int base_ = row_ * 128 + (((c + row_) & 15) << 3) + ((g & 1) << 2); \
      *(half4v*)&svhc[base_] = zh4_; \
      f32x4 ms_ = mf_; \
      _Pragma("unroll") for (int r = 0; r < 4; ++r) { \
        float x_ = ms_[r]; \
        x_ += __shfl_xor(x_, 1); x_ += __shfl_xor(x_, 2); \
        x_ += __shfl_xor(x_, 4); x_ += __shfl_xor(x_, 8); \
        ms_[r] = x_ * 0.0625f; } \
      if (c == 0) *(f32x4*)(mf_p + mt * 64) = ms_; \
    } \
    zf_p += 512; mf_p += 512; \
    qpl_ += __shfl_xor(qpl_, 16); \
    qpl_ += __shfl_xor(qpl_, 32); \
    if (g == 0) qppc[BI][wvc * 16 + c] = qpl_; \
  } while (0)

#define PHASE_B(BI, QIV) do { \
    half8v hf_[8]; \
    _Pragma("unroll") for (int kt = 0; kt < 8; ++kt) { \
      int row_ = kt * 4 + g; \
      hf_[kt] = *(const half8v*)&hbc[row_ * 128 + (((c + row_) & 15) << 3)]; } \
    f32x4 a2a_[2], a2b_[2]; \
    _Pragma("unroll") for (int mt = 0; mt < 2; ++mt) { a2a_[mt] = (f32x4){0,0,0,0}; a2b_[mt] = (f32x4){0,0,0,0}; } \
    _Pragma("unroll") for (int kt = 0; kt < 4; ++kt) \
      _Pragma("unroll") for (int mt = 0; mt < 2; ++mt) { \
        a2a_[mt] = MFMA32(w2f[mt][kt], hf_[kt], a2a_[mt]); \
        a2b_[mt] = MFMA32(w2f[mt][kt + 4], hf_[kt + 4], a2b_[mt]); } \
    f32x4 mv_[2]; \
    _Pragma("unroll") for (int mt = 0; mt < 2; ++mt) { \
      mv_[mt] = zreg[mt] + a2a_[mt] + a2b_[mt]; \
      if (wvc < 2) mv_[mt] += ur##BI[mt]; } \
    EPILOG(BI, QIV, mv_); \
  } while (0)

#define KL_FIN(PBI, TPREV) do { \
    if (ct < 16) { \
      float v_ = qppc[PBI][ct] + qppc[PBI][16 + ct] + qppc[PBI][32 + ct] + qppc[PBI][48 + ct]; \
      v_ += __shfl_xor(v_, 1); v_ += __shfl_xor(v_, 2); \
      v_ += __shfl_xor(v_, 4); v_ += __shfl_xor(v_, 8); \
      if (ct == 0) out_kl[(size_t)b * 256 + (size_t)(TPREV)] = 0.03125f * v_ + kv##PBI; \
    } \
  } while (0)

  // ---------------- t = 0 ----------------
  STAGE(0);
  STAGE(1);
  {
    f32x4 mv0[2];
#pragma unroll
    for (int mt = 0; mt < 2; ++mt) {
      mv0[mt] = *(const f32x4*)&m_init[wvc * 32 + mt * 16 + g * 4];
      if (wvc < 2) mv0[mt] += ur0[mt];
    }
    half4v mh0[2], ml0[2];
#pragma unroll
    for (int kt = 0; kt < 2; ++kt)
#pragma unroll
      for (int j = 0; j < 4; ++j) {
        float x = mv0[kt][j];
        _Float16 h = (_Float16)x;
        mh0[kt][j] = h;
        ml0[kt][j] = (_Float16)(x - (float)h);
      }
    half4v ka0_, ka1_;
    KAH(0, 0, ka0_); KAH(0, 1, ka1_);
    f32x4 hz = {0, 0, 0, 0};
    hz = MFMA16(ka0_, mh0[0], hz); hz = MFMA16(ka1_, mh0[1], hz);
    hz = MFMA16(ka0_, ml0[0], hz); hz = MFMA16(ka1_, ml0[1], hz);
    *(f32x4*)&h2pc[wvc][c * 20 + g * 4] = hz;
    BAR();
    EPILOG(0, qiv0, mv0);
    BAR();
  }

  // ---------------- t = 1..254 (pairs) ----------------
  for (int t = 1; t < 255; t += 2) {
    KL_FIN(0, t - 1);
    STAGE(0);
    PHASE_A(1);
    BAR();
    PHASE_B(1, qiv);
    BAR();
    KL_FIN(1, t);
    STAGE(1);
    PHASE_A(0);
    BAR();
    PHASE_B(0, qiv);
    BAR();
  }
  // ---------------- t = 255 ----------------
  KL_FIN(0, 254);
  PHASE_A(1);
  BAR();
  PHASE_B(1, qiv);
  BAR();
  KL_FIN(1, 255);

#undef STAGE
#undef KAH
#undef PHASE_A
#undef EPILOG
#undef PHASE_B
#undef KL_FIN
}

// ============ kscan1: 256 threads, one chain ============
template <bool PK, int ZMODE>
__launch_bounds__(256, 1)
__global__ void kscan1_kernel(const float* __restrict__ ug, const float* __restrict__ Kg,
                              const float* __restrict__ W1, const float* __restrict__ W2,
                              const float* __restrict__ m_init, const float* __restrict__ Qd,
                              const float* __restrict__ Q0d, const _Float16* __restrict__ pfb,
                              const float* __restrict__ cgp, const _Float16* __restrict__ rfb,
                              const _Float16* __restrict__ kab, const float* __restrict__ zpcb,
                              const float* __restrict__ klcp, float* __restrict__ out_zf,
                              float* __restrict__ out_mf, float* __restrict__ out_kl) {
  __shared__ __align__(16) _Float16 svh[2048];
  __shared__ __align__(16) _Float16 hb[4096];
  __shared__ float h2p[4][320];
  __shared__ float qpp[2][64];
  scan_body<PK, ZMODE>(blockIdx.x, threadIdx.x, svh, hb, h2p, qpp,
                       ug, Kg, W1, W2, m_init, Qd, Q0d, pfb, cgp, rfb, kab, zpcb, klcp,
                       out_zf, out_mf, out_kl);
}

// ============ kc3: noise path + R frags from kab f16; zpc written as f16 fragments ============
__global__ void kc3_kernel(const _Float16* __restrict__ kab, const float* __restrict__ epsz,
                           const float* __restrict__ epsw, const float* __restrict__ Qd,
                           const float* __restrict__ Q0d, const float* __restrict__ Ainv,
                           const _Float16* __restrict__ w2h, _Float16* __restrict__ rfb,
                           _Float16* __restrict__ zpch, float* __restrict__ out_zp) {
  int idx = blockIdx.x;
  int t = idx >> 6, b = idx & 63;
  size_t bt = (size_t)b * 256 + t;
  int tid = threadIdx.x;
  const int wv = tid >> 6, ln = tid & 63, g = ln >> 4, c = ln & 15;
  __shared__ _Float16 Ksh[128][18];
  __shared__ float Ai[16][16];
  __shared__ __align__(16) float zp[16][132];
  __shared__ float hh[16][17];
  __shared__ float ww[16][17];
  __shared__ float sq[128];
  __shared__ _Float16 Rh[16][264];
  {
    half8v ko = *(const half8v*)(kab + bt * 2048 + (size_t)tid * 8);
#pragma unroll
    for (int kt = 0; kt < 2; ++kt)
#pragma unroll
      for (int j = 0; j < 4; ++j)
        Ksh[wv * 32 + kt * 16 + g * 4 + j][c] = ko[kt * 4 + j];
  }
  ((float*)Ai)[tid] = Ainv[bt * 256 + tid];
  const float* q = (t == 0) ? Q0d : Qd;
  if (tid < 128) sq[tid] = sqrtf(q[tid]);
  __syncthreads();
  {
    const f32x4* ez4 = (const f32x4*)(epsz + ((size_t)t * 16 * 64) * 128);
    f32x4* ozp4 = (f32x4*)out_zp;
    for (int i = tid; i < 512; i += 256) {
      int s = i >> 5, l4 = i & 31;
      f32x4 e = ez4[((size_t)s * 64 + b) * 32 + l4];
      f32x4 sv = *(const f32x4*)&sq[l4 * 4];
      f32x4 v = e * sv;
      *(f32x4*)&zp[s][l4 * 4] = v;
      ozp4[(((size_t)s * 64 + b) * 256 + t) * 32 + l4] = v;
    }
  }
  {
    half8v kA[4];
#pragma unroll
    for (int kt = 0; kt < 4; ++kt)
#pragma unroll
      for (int j = 0; j < 8; ++j) kA[kt][j] = Ksh[kt * 32 + g * 8 + j][c];
#pragma unroll
    for (int i = 0; i < 4; ++i) {
      int tile = wv * 4 + i;
      f32x4 acc = {0, 0, 0, 0};
#pragma unroll
      for (int kt = 0; kt < 4; ++kt) {
        half8v bf = *(const half8v*)&w2h[(size_t)(tile * 16 + c) * 128 + kt * 32 + g * 8];
        acc = MFMA32(kA[kt], bf, acc);
      }
#pragma unroll
      for (int r = 0; r < 4; ++r) Rh[g * 4 + r][tile * 16 + c] = (_Float16)acc[r];
    }
  }
  __syncthreads();
  {
    int s = tid >> 4, r = tid & 15;
    float acc = epsw[(((size_t)t * 16 + s) * 64 + b) * 16 + r];
    for (int l = 0; l < 128; ++l) acc += (float)Ksh[l][r] * zp[s][l];
    hh[s][r] = acc;
  }
  {
    half8v r0, r1;
#pragma unroll
    for (int mt = 0; mt < 4; ++mt)
#pragma unroll
      for (int j = 0; j < 4; ++j) {
        _Float16 v = Rh[c][wv * 64 + mt * 16 + g * 4 + j];
        if (mt < 2) r0[mt * 4 + j] = v; else r1[(mt - 2) * 4 + j] = v;
      }
    *(half8v*)(rfb + bt * 4096 + (size_t)tid * 16) = r0;
    *(half8v*)(rfb + bt * 4096 + (size_t)tid * 16 + 8) = r1;
  }
  __syncthreads();
  {
    int s = tid >> 4, r = tid & 15;
    float acc = 0.f;
    for (int j = 0; j < 16; ++j) acc += Ai[r][j] * hh[s][j];
    ww[s][r] = acc;
  }
  __syncthreads();
  // zpc fragments (f16), scan-thread order: thread tid -> s=c, l = wv*32 + mt*16 + g*4 + j
  {
    half8v zo;
#pragma unroll
    for (int mt = 0; mt < 2; ++mt)
#pragma unroll
      for (int j = 0; j < 4; ++j) {
        int l = wv * 32 + mt * 16 + g * 4 + j;
        float acc = 0.f;
#pragma unroll
        for (int r = 0; r < 16; ++r) acc += (float)Ksh[l][r] * ww[c][r];
        zo[mt * 4 + j] = (_Float16)(zp[c][l] - acc);
      }
    *(half8v*)(zpch + bt * 2048 + (size_t)tid * 8) = zo;
  }
}

// ============ kprep1 (round-12 proven): A, chol, Ainv, klc, pf, c', kab ============
__global__ void kprep1_kernel(const float* __restrict__ Kg, const float* __restrict__ kg,
                              const float* __restrict__ ug, const float* __restrict__ Qd,
                              const float* __restrict__ Q0d, float* __restrict__ Ainv,
                              float* __restrict__ klc, _Float16* __restrict__ pfb,
                              float* __restrict__ cgp, _Float16* __restrict__ kab) {
  int tid = threadIdx.x;
  int wv = tid >> 6, ln = tid & 63;
  size_t bt = (size_t)blockIdx.x * 4 + wv;
  int t = (int)(bt & 255);
  __shared__ __align__(16) float Ks[4][128][20];
  __shared__ float qs[4][128];
  __shared__ float vvs[4][128];
  __shared__ float Asm[4][16][20];
  __shared__ float LiL[4][16][20];
  __shared__ float AiS[4][16][20];
  __shared__ float yps[4][4][16];
  __shared__ float yvs[4][16];
  const f32x4* kp4 = (const f32x4*)(Kg + bt * 2048);
  for (int i = ln; i < 512; i += 64) {
    f32x4 v = kp4[i];
    *(f32x4*)&Ks[wv][i >> 2][(i & 3) * 4] = v;
  }
  for (int l = ln; l < 128; l += 64) {
    float q = (t == 0) ? Q0d[l] : Qd[l];
    qs[wv][l] = q;
    float v = Qd[l] * kg[bt * 128 + l];
    if (t > 0 && l < 64) v += ug[bt * 64 + l];
    vvs[wv][l] = v;
  }
  __syncthreads();
  if (kab) {
    int gg = ln >> 4, cc2 = ln & 15;
#pragma unroll
    for (int q = 0; q < 4; ++q) {
      half8v ko;
#pragma unroll
      for (int kt = 0; kt < 2; ++kt)
#pragma unroll
        for (int j = 0; j < 4; ++j)
          ko[kt * 4 + j] = (_Float16)Ks[wv][q * 32 + kt * 16 + gg * 4 + j][cc2];
      *(half8v*)(kab + bt * 2048 + (size_t)(q * 64 + ln) * 8) = ko;
    }
  }
  {
    int r = ln & 15, c0 = (ln >> 4) << 2;
    float a0 = 0, a1 = 0, a2 = 0, a3 = 0;
    for (int l = 0; l < 128; ++l) {
      float kq = Ks[wv][l][r] * qs[wv][l];
      const float* row = &Ks[wv][l][c0];
      a0 += kq * row[0]; a1 += kq * row[1]; a2 += kq * row[2]; a3 += kq * row[3];
    }
    Asm[wv][r][c0 + 0] = a0 + ((r == c0 + 0) ? 1.f : 0.f);
    Asm[wv][r][c0 + 1] = a1 + ((r == c0 + 1) ? 1.f : 0.f);
    Asm[wv][r][c0 + 2] = a2 + ((r == c0 + 2) ? 1.f : 0.f);
    Asm[wv][r][c0 + 3] = a3 + ((r == c0 + 3) ? 1.f : 0.f);
  }
  {
    int r = ln & 15, seg = ln >> 4;
    float s = 0.f;
    for (int l = seg * 32; l < seg * 32 + 32; ++l) s += Ks[wv][l][r] * vvs[wv][l];
    yps[wv][seg][r] = s;
  }
  __syncthreads();
  if (ln < 16) {
    int i = ln;
    float ar[16], Lr[16];
#pragma unroll
    for (int j = 0; j < 16; ++j) ar[j] = Asm[wv][i][j];
    float ld = 0.f;
#pragma unroll
    for (int j = 0; j < 16; ++j) {
      float ajj = __shfl(ar[j], j, 64);
      float d = sqrtf(ajj);
      ld += __logf(d);
      float li = ar[j] / d;
      li = (i >= j) ? li : 0.f;
      Lr[j] = li;
#pragma unroll
      for (int k2 = j; k2 < 16; ++k2) {
        float lk = __shfl(li, k2, 64);
        ar[k2] -= li * lk;
      }
    }
    int cc = i;
    float Lic[16];
#pragma unroll
    for (int ii = 0; ii < 16; ++ii) {
      float s = (ii == cc) ? 1.f : 0.f;
#pragma unroll
      for (int p = 0; p < 16; ++p) {
        if (p < ii) {
          float Lip = __shfl(Lr[p], ii, 64);
          s -= Lip * Lic[p];
        }
      }
      float dii = __shfl(Lr[ii], ii, 64);
      float v = s / dii;
      Lic[ii] = (ii >= cc) ? v : 0.f;
    }
    float tr = 0.f;
#pragma unroll
    for (int ii = 0; ii < 16; ++ii) { tr += Lic[ii] * Lic[ii]; LiL[wv][cc][ii] = Lic[ii]; }
    tr += __shfl_xor(tr, 1); tr += __shfl_xor(tr, 2);
    tr += __shfl_xor(tr, 4); tr += __shfl_xor(tr, 8);
    if (cc == 0) klc[bt] = 0.5f * (tr - 16.f + 2.f * ld);
    yvs[wv][cc] = yps[wv][0][cc] + yps[wv][1][cc] + yps[wv][2][cc] + yps[wv][3][cc];
  }
  __syncthreads();
  {
    int r = ln & 15, c0 = (ln >> 4) << 2;
    float a0 = 0, a1 = 0, a2 = 0, a3 = 0;
    for (int ii = 0; ii < 16; ++ii) {
      float lir = LiL[wv][r][ii];
      a0 += lir * LiL[wv][c0 + 0][ii];
      a1 += lir * LiL[wv][c0 + 1][ii];
      a2 += lir * LiL[wv][c0 + 2][ii];
      a3 += lir * LiL[wv][c0 + 3][ii];
    }
    AiS[wv][r][c0 + 0] = a0; AiS[wv][r][c0 + 1] = a1;
    AiS[wv][r][c0 + 2] = a2; AiS[wv][r][c0 + 3] = a3;
    f32x4 av = {a0, a1, a2, a3};
    *(f32x4*)&Ainv[bt * 256 + r * 16 + c0] = av;
  }
  __syncthreads();
  {
#pragma unroll
    for (int li = 0; li < 2; ++li) {
      int l = ln * 2 + li;
      f32x4 acc0 = {0,0,0,0}, acc1v = {0,0,0,0}, acc2v = {0,0,0,0}, acc3v = {0,0,0,0};
      for (int j = 0; j < 16; ++j) {
        float kj = Ks[wv][l][j];
        acc0  += kj * *(const f32x4*)&AiS[wv][j][0];
        acc1v += kj * *(const f32x4*)&AiS[wv][j][4];
        acc2v += kj * *(const f32x4*)&AiS[wv][j][8];
        acc3v += kj * *(const f32x4*)&AiS[wv][j][12];
      }
      float ql = qs[wv][l];
      float cp = ql * kg[bt * 128 + l];
      float pv[16];
#pragma unroll
      for (int e = 0; e < 4; ++e) {
        pv[e] = ql * acc0[e]; pv[4 + e] = ql * acc1v[e];
        pv[8 + e] = ql * acc2v[e]; pv[12 + e] = ql * acc3v[e];
      }
#pragma unroll
      for (int r = 0; r < 16; ++r) cp -= pv[r] * yvs[wv][r];
      cgp[bt * 128 + l] = cp;
#pragma unroll
      for (int r = 0; r < 16; ++r) Ks[wv][l][r] = pv[r];
    }
  }
  __syncthreads();
  {
    int gp = ln >> 4, cp = ln & 15;
#pragma unroll
    for (int ci = 0; ci < 4; ++ci) {
      half8v o;
#pragma unroll
      for (int mt = 0; mt < 2; ++mt)
#pragma unroll
        for (int j = 0; j < 4; ++j)
          o[mt * 4 + j] = (_Float16)Ks[wv][ci * 32 + mt * 16 + cp][gp * 4 + j];
      *(half8v*)(pfb + bt * 2048 + (size_t)(ci * 64 + ln) * 8) = o;
    }
  }
}

// ============ round-7 small-ws fallback kernels ============
__global__ void kprepR_kernel(const float* __restrict__ Kg, const _Float16* __restrict__ w2h,
                              _Float16* __restrict__ rfb, _Float16* __restrict__ kab) {
  int tid = threadIdx.x;
  int wv = tid >> 6, ln = tid & 63;
  int g = ln >> 4, c = ln & 15;
  __shared__ _Float16 Kh[128][20];
  __shared__ _Float16 Rh[16][264];
  for (int it = 0; it < 4; ++it) {
    size_t bt = (size_t)blockIdx.x * 4 + it;
    const float* kp = Kg + bt * 2048;
    for (int i = tid; i < 2048; i += 256) Kh[i >> 4][i & 15] = (_Float16)kp[i];
    __syncthreads();
    half8v kA[4];
#pragma unroll
    for (int kt = 0; kt < 4; ++kt)
#pragma unroll
      for (int j = 0; j < 8; ++j) kA[kt][j] = Kh[kt * 32 + g * 8 + j][c];
#pragma unroll
    for (int i = 0; i < 4; ++i) {
      int tile = wv * 4 + i;
      f32x4 acc = {0, 0, 0, 0};
#pragma unroll
      for (int kt = 0; kt < 4; ++kt) {
        half8v bf = *(const half8v*)&w2h[(size_t)(tile * 16 + c) * 128 + kt * 32 + g * 8];
        acc = MFMA32(kA[kt], bf, acc);
      }
#pragma unroll
      for (int r = 0; r < 4; ++r) Rh[g * 4 + r][tile * 16 + c] = (_Float16)acc[r];
    }
    __syncthreads();
    half8v r0, r1;
#pragma unroll
    for (int mt = 0; mt < 4; ++mt)
#pragma unroll
      for (int j = 0; j < 4; ++j) {
        _Float16 v = Rh[c][wv * 64 + mt * 16 + g * 4 + j];
        if (mt < 2) r0[mt * 4 + j] = v; else r1[(mt - 2) * 4 + j] = v;
      }
    *(half8v*)(rfb + bt * 4096 + (size_t)tid * 16) = r0;
    *(half8v*)(rfb + bt * 4096 + (size_t)tid * 16 + 8) = r1;
    if (kab) {
      half8v ko;
#pragma unroll
      for (int kt = 0; kt < 2; ++kt)
#pragma unroll
        for (int j = 0; j < 4; ++j) ko[kt * 4 + j] = Kh[wv * 32 + kt * 16 + g * 4 + j][c];
      *(half8v*)(kab + bt * 2048 + (size_t)tid * 8) = ko;
    }
    __syncthreads();
  }
}

__global__ void kc_kernel(const float* __restrict__ Kg, const float* __restrict__ epsz,
                          const float* __restrict__ epsw, const float* __restrict__ Qd,
                          const float* __restrict__ Q0d, const float* __restrict__ Ainv,
                          float* __restrict__ out_zf, float* __restrict__ out_zp,
                          float* __restrict__ zpcb, int zw, int wzp) {
  int idx = blockIdx.x;
  int t = idx >> 6, b = idx & 63;
  int bt = b * 256 + t;
  __shared__ float Ks[128][16];
  __shared__ float Ai[16][16];
  __shared__ float zp[16][129];
  __shared__ float hh[16][17];
  __shared__ float ww[16][17];
  __shared__ float sq[128];
  const float* kp = Kg + (size_t)bt * 2048;
  for (int i = threadIdx.x; i < 2048; i += 256) ((float*)Ks)[i] = kp[i];
  ((float*)Ai)[threadIdx.x] = Ainv[(size_t)bt * 256 + threadIdx.x];
  const float* q = (t == 0) ? Q0d : Qd;
  if (threadIdx.x < 128) sq[threadIdx.x] = sqrtf(q[threadIdx.x]);
  __syncthreads();
  for (int i = threadIdx.x; i < 2048; i += 256) {
    int s = i >> 7, l = i & 127;
    float v = sq[l] * epsz[(((size_t)t * 16 + s) * 64 + b) * 128 + l];
    zp[s][l] = v;
    if (wzp) out_zp[(((size_t)s * 64 + b) * 256 + t) * 128 + l] = v;
  }
  __syncthreads();
  {
    int s = threadIdx.x >> 4, r = threadIdx.x & 15;
    float acc = epsw[(((size_t)t * 16 + s) * 64 + b) * 16 + r];
    for (int l = 0; l < 128; ++l) acc += Ks[l][r] * zp[s][l];
    hh[s][r] = acc;
  }
  __syncthreads();
  {
    int s = threadIdx.x >> 4, r = threadIdx.x & 15;
    float acc = 0.f;
    for (int j = 0; j < 16; ++j) acc += Ai[r][j] * hh[s][j];
    ww[s][r] = acc;
  }
  __syncthreads();
  for (int i = threadIdx.x; i < 2048; i += 256) {
    int s = i >> 7, l = i & 127;
    float acc = 0.f;
    for (int r = 0; r < 16; ++r) acc += Ks[l][r] * ww[s][r];
    float v = zp[s][l] - acc;
    if (zw) zpcb[(size_t)bt * 2048 + i] = v;
    else out_zf[(((size_t)s * 64 + b) * 256 + t) * 128 + l] = v;
  }
}

__global__ void kzp_kernel(const float* __restrict__ epsz, const float* __restrict__ Qd,
                           const float* __restrict__ Q0d, float* __restrict__ out_zp) {
  for (size_t i = (size_t)blockIdx.x * blockDim.x + threadIdx.x; i < (size_t)33554432;
       i += (size_t)gridDim.x * blockDim.x) {
    int l = (int)(i & 127);
    int t = (int)((i >> 7) & 255);
    int sb = (int)(i >> 15);
    int s = sb >> 6, b = sb & 63;
    float q = (t == 0) ? Q0d[l] : Qd[l];
    out_zp[i] = sqrtf(q) * epsz[(((size_t)t * 16 + s) * 64 + b) * 128 + l];
  }
}

extern "C" void kernel_launch(void* const* d_in, const int* in_sizes, int n_in,
                              void* d_out, int out_size, void* d_ws, size_t ws_size,
                              hipStream_t stream) {
  (void)in_sizes; (void)n_in; (void)out_size;
  const float* u   = (const float*)d_in[0];
  const float* kk  = (const float*)d_in[1];
  const float* Kg  = (const float*)d_in[2];
  const float* epz = (const float*)d_in[3];
  const float* epw = (const float*)d_in[4];
  const float* W1  = (const float*)d_in[5];
  const float* W2  = (const float*)d_in[6];
  const float* mi  = (const float*)d_in[7];
  const float* Qd  = (const float*)d_in[8];
  const float* Q0d = (const float*)d_in[9];

  float* out_zf = (float*)d_out;
  float* out_mf = out_zf + (size_t)33554432;
  float* out_zp = out_mf + (size_t)2097152;
  float* out_kl = out_zp + (size_t)33554432;

  char* ws = (char*)d_ws;

  // ---- primary plan (zpc now f16: 67,108,864) ----
  const size_t F_klc  = 0;                 // 65,536
  const size_t F_cgp  = 65536;             // 8,388,608
  const size_t F_pfb  = 8454144;           // 67,108,864
  const size_t F_w2h  = 75563008;          // 65,536
  const size_t F_kab  = 75628544;          // 67,108,864
  const size_t F_rfb  = 142737408;         // 134,217,728
  const size_t F_zpc  = 276955136;         // 67,108,864 (f16)
  const size_t F_ainv = 344064000;         // 16,777,216
  const size_t F_END  = 360841216;

  if (ws_size >= F_END) {
    float*    klc  = (float*)(ws + F_klc);
    float*    cgp  = (float*)(ws + F_cgp);
    _Float16* pfb  = (_Float16*)(ws + F_pfb);
    _Float16* w2h  = (_Float16*)(ws + F_w2h);
    _Float16* kab  = (_Float16*)(ws + F_kab);
    _Float16* rfb  = (_Float16*)(ws + F_rfb);
    _Float16* zpch = (_Float16*)(ws + F_zpc);
    float*    Ainv = (float*)(ws + F_ainv);
    kw2_kernel<<<128, 256, 0, stream>>>(W2, w2h);
    kprep1_kernel<<<4096, 256, 0, stream>>>(Kg, kk, u, Qd, Q0d, Ainv, klc, pfb, cgp, kab);
    kc3_kernel<<<16384, 256, 0, stream>>>(kab, epz, epw, Qd, Q0d, Ainv, w2h,
                                          rfb, zpch, out_zp);
    kscan1_kernel<true, 2><<<64, 256, 0, stream>>>(u, Kg, W1, W2, mi, Qd, Q0d, pfb,
                                                   cgp, rfb, kab, (const float*)zpch, klc,
                                                   out_zf, out_mf, out_kl);
    return;
  }

  // ---- small-ws fallback (round-7 path) ----
  size_t off = 0;
  auto take = [&](size_t n) { char* p = ws + off; off += n; return p; };
  float*    Ainv = (float*)take(16777216);
  float*    klc  = (float*)take(65536);
  float*    cgp  = (float*)take(8388608);
  _Float16* pfb  = (_Float16*)take(67108864);
  _Float16* w2h  = (_Float16*)take(65536);
  bool zw = ws_size >= off + 134217728;
  float* zpcb = zw ? (float*)take(134217728) : nullptr;
  bool pk = zw && (ws_size >= off + 67108864);
  _Float16* kab = pk ? (_Float16*)take(67108864) : nullptr;
  bool rfws = ws_size >= off + 134217728;
  _Float16* rfb = rfws ? (_Float16*)take(134217728) : (_Float16*)out_zp;
  int wzp = rfws ? 1 : 0;

  kw2_kernel<<<128, 256, 0, stream>>>(W2, w2h);
  kprep1_kernel<<<4096, 256, 0, stream>>>(Kg, kk, u, Qd, Q0d, Ainv, klc, pfb, cgp, nullptr);
  kprepR_kernel<<<4096, 256, 0, stream>>>(Kg, w2h, rfb, kab);
  kc_kernel<<<16384, 256, 0, stream>>>(Kg, epz, epw, Qd, Q0d, Ainv, out_zf, out_zp,
                                       zpcb, zw ? 1 : 0, wzp);
  if (pk)
    kscan1_kernel<true, 1><<<64, 256, 0, stream>>>(u, Kg, W1, W2, mi, Qd, Q0d, pfb, cgp, rfb, kab, zpcb, klc, out_zf, out_mf, out_kl);
  else if (zw)
    kscan1_kernel<false, 1><<<64, 256, 0, stream>>>(u, Kg, W1, W2, mi, Qd, Q0d, pfb, cgp, rfb, kab, zpcb, klc, out_zf, out_mf, out_kl);
  else
    kscan1_kernel<false, 0><<<64, 256, 0, stream>>>(u, Kg, W1, W2, mi, Qd, Q0d, pfb, cgp, rfb, kab, zpcb, klc, out_zf, out_mf, out_kl);
  if (!rfws) kzp_kernel<<<2048, 256, 0, stream>>>(epz, Qd, Q0d, out_zp);
}

// Round 16
// 967.552 us; speedup vs baseline: 2.1993x; 1.0360x over previous
//
#include <hip/hip_runtime.h>
#include <cstddef>

typedef _Float16 half8v __attribute__((ext_vector_type(8)));
typedef _Float16 half4v __attribute__((ext_vector_type(4)));
typedef float f32x4 __attribute__((ext_vector_type(4)));

#define MFMA32(A, B, C) __builtin_amdgcn_mfma_f32_16x16x32_f16(A, B, C, 0, 0, 0)
#define MFMA16(A, B, C) __builtin_amdgcn_mfma_f32_16x16x16f16(A, B, C, 0, 0, 0)

// ============ kw2: W2 -> f16 copy ============
__global__ void kw2_kernel(const float* __restrict__ W2, _Float16* __restrict__ w2h) {
  int i = blockIdx.x * 256 + threadIdx.x;
  w2h[i] = (_Float16)W2[i];
}

#define BAR() asm volatile("s_waitcnt lgkmcnt(0)\n\ts_barrier" ::: "memory")

// ============ scan body (round-7 proven) ============
// ZMODE: 0 = zpc aliased in out_zf (f32), 1 = zpcb f32, 2 = zpcb f16 fragments
template <bool PK, int ZMODE>
__device__ __forceinline__ void scan_body(
    const int b, const int ct,
    _Float16* __restrict__ svhc, _Float16* __restrict__ hbc,
    float (*__restrict__ h2pc)[320], float (*__restrict__ qppc)[64],
    const float* __restrict__ ug, const float* __restrict__ Kg,
    const float* __restrict__ W1, const float* __restrict__ W2,
    const float* __restrict__ m_init, const float* __restrict__ Qd,
    const float* __restrict__ Q0d, const _Float16* __restrict__ pfb,
    const float* __restrict__ cgp, const _Float16* __restrict__ rfb,
    const _Float16* __restrict__ kab, const float* __restrict__ zpcb,
    const float* __restrict__ klcp, float* __restrict__ out_zf,
    float* __restrict__ out_mf, float* __restrict__ out_kl) {
  const int wvc = ct >> 6;
  const int ln = ct & 63;
  const int g = ln >> 4;
  const int c = ln & 15;

  half8v w1f[4][4];
#pragma unroll
  for (int mt = 0; mt < 4; ++mt)
#pragma unroll
    for (int kt = 0; kt < 4; ++kt) {
      half8v v;
#pragma unroll
      for (int j = 0; j < 8; ++j)
        v[j] = (_Float16)W1[(size_t)(kt * 32 + g * 8 + j) * 256 + (wvc * 64 + mt * 16 + c)];
      w1f[mt][kt] = v;
    }
  half8v w2f[2][8];
#pragma unroll
  for (int mt = 0; mt < 2; ++mt)
#pragma unroll
    for (int kt = 0; kt < 8; ++kt) {
      half8v v;
#pragma unroll
      for (int j = 0; j < 8; ++j)
        v[j] = (_Float16)W2[(size_t)(kt * 32 + g * 8 + j) * 128 + (wvc * 32 + mt * 16 + c)];
      w2f[mt][kt] = v;
    }

  f32x4 qiv[2], qiv0[2];
#pragma unroll
  for (int mt = 0; mt < 2; ++mt) {
    f32x4 q = *(const f32x4*)&Qd[wvc * 32 + mt * 16 + g * 4];
    f32x4 q0 = *(const f32x4*)&Q0d[wvc * 32 + mt * 16 + g * 4];
#pragma unroll
    for (int r = 0; r < 4; ++r) { qiv[mt][r] = 1.f / q[r]; qiv0[mt][r] = 1.f / q0[r]; }
  }

  f32x4 zreg[2];

  half8v pfx0, pfx1, kax0 = {}, kax1 = {}, rfa0, rfa1, rfc0, rfc1;
  float kf0[8], kf1[8];
  f32x4 zq0[2], zq1[2], cv0[2], cv1[2];
  f32x4 ur0[2] = {}, ur1[2] = {};
  float kv0 = 0.f, kv1 = 0.f;

  const char* pf_p = (const char*)pfb + (size_t)b * 256 * 4096 + (size_t)ct * 16;
  const char* ka_p = PK ? (const char*)kab + (size_t)b * 256 * 4096 + (size_t)ct * 16
                        : (const char*)pfb;
  const char* K_p = (const char*)Kg + (size_t)b * 256 * 8192 + (size_t)((wvc * 32 + g * 4) * 16 + c) * 4;
  const char* rf_p = (const char*)rfb + (size_t)b * 256 * 8192 + (size_t)ct * 32;
  const char* zq_p;
  size_t zq_str;
  if constexpr (ZMODE == 2) {
    zq_p = (const char*)zpcb + (size_t)b * 256 * 4096 + (size_t)ct * 16;
    zq_str = 4096;
  } else if constexpr (ZMODE == 1) {
    zq_p = (const char*)zpcb + (size_t)b * 256 * 8192 + (size_t)(c * 128 + wvc * 32 + g * 4) * 4;
    zq_str = 8192;
  } else {
    zq_p = (const char*)out_zf + ((((size_t)c * 64 + b) * 256) * 128 + wvc * 32 + g * 4) * 4;
    zq_str = 512;
  }
  const char* cv_p = (const char*)cgp + (size_t)b * 256 * 512 + (size_t)(wvc * 32 + g * 4) * 4;
  const char* ur_p = (const char*)ug + (size_t)b * 256 * 256 + (size_t)(wvc * 32 + g * 4) * 4;
  const char* kl_p = (const char*)klcp + (size_t)b * 256 * 4;
  char* zf_p = (char*)out_zf + ((((size_t)c * 64 + b) * 256) * 128 + wvc * 32 + g * 4) * 4;
  char* mf_p = (char*)out_mf + ((size_t)b * 256 * 128 + wvc * 32 + g * 4) * 4;

#define STAGE(BI) do { \
    pfx##BI = *(const half8v*)pf_p; pf_p += 4096; \
    if constexpr (PK) { kax##BI = *(const half8v*)ka_p; ka_p += 4096; } \
    else { _Pragma("unroll") for (int kt_ = 0; kt_ < 2; ++kt_) \
             _Pragma("unroll") for (int j_ = 0; j_ < 4; ++j_) \
               kf##BI[kt_ * 4 + j_] = *(const float*)(K_p + kt_ * 1024 + j_ * 64); \
           K_p += 8192; } \
    rfa##BI = *(const half8v*)rf_p; rfc##BI = *(const half8v*)(rf_p + 16); rf_p += 8192; \
    if constexpr (ZMODE == 2) { \
      half8v zo_ = *(const half8v*)zq_p; \
      _Pragma("unroll") for (int j_ = 0; j_ < 4; ++j_) { \
        zq##BI[0][j_] = (float)zo_[j_]; zq##BI[1][j_] = (float)zo_[4 + j_]; } \
    } else { \
      zq##BI[0] = *(const f32x4*)zq_p; zq##BI[1] = *(const f32x4*)(zq_p + 64); \
    } \
    zq_p += zq_str; \
    cv##BI[0] = *(const f32x4*)cv_p; cv##BI[1] = *(const f32x4*)(cv_p + 64); cv_p += 512; \
    if (wvc < 2) { ur##BI[0] = *(const f32x4*)ur_p; ur##BI[1] = *(const f32x4*)(ur_p + 64); } \
    ur_p += 256; \
    kv##BI = *(const float*)kl_p; kl_p += 4; \
  } while (0)

#define KAH(BI, KT, DST) do { \
    if constexpr (PK) { _Pragma("unroll") for (int j_ = 0; j_ < 4; ++j_) DST[j_] = kax##BI[(KT) * 4 + j_]; } \
    else { _Pragma("unroll") for (int j_ = 0; j_ < 4; ++j_) DST[j_] = (_Float16)kf##BI[(KT) * 4 + j_]; } \
  } while (0)

#define PHASE_A(BI) do { \
    half4v zbh_[2], zbl_[2]; \
    _Pragma("unroll") for (int kt = 0; kt < 2; ++kt) \
      _Pragma("unroll") for (int j = 0; j < 4; ++j) { \
        float x_ = zreg[kt][j]; _Float16 h_ = (_Float16)x_; \
        zbh_[kt][j] = h_; zbl_[kt][j] = (_Float16)(x_ - (float)h_); } \
    half8v zh8_[4]; \
    _Pragma("unroll") for (int kt = 0; kt < 4; ++kt) { \
      int row_ = kt * 4 + g; \
      int idx_ = row_ * 128 + (((c + row_) & 15) << 3); \
      zh8_[kt] = *(const half8v*)&svhc[idx_]; } \
    f32x4 a1h_[4]; \
    _Pragma("unroll") for (int mt = 0; mt < 4; ++mt) a1h_[mt] = (f32x4){0,0,0,0}; \
    _Pragma("unroll") for (int kt = 0; kt < 4; ++kt) \
      _Pragma("unroll") for (int mt = 0; mt < 4; ++mt) \
        a1h_[mt] = MFMA32(w1f[mt][kt], zh8_[kt], a1h_[mt]); \
    half4v th_[4]; \
    _Pragma("unroll") for (int mt = 0; mt < 4; ++mt) { \
      _Pragma("unroll") for (int r = 0; r < 4; ++r) { \
        float x_ = a1h_[mt][r]; \
        float e_ = __expf(2.f * x_); \
        th_[mt][r] = (_Float16)(1.f - 2.f / (e_ + 1.f)); } \
      int row_ = wvc * 8 + mt * 2 + (g >> 1); \
      *(half4v*)&hbc[row_ * 128 + (((c + row_) & 15) << 3) + ((g & 1) << 2)] = th_[mt]; } \
    half4v ka0_, ka1_; KAH(BI, 0, ka0_); KAH(BI, 1, ka1_); \
    f32x4 hz_ = {0, 0, 0, 0}; \
    hz_ = MFMA16(ka0_, zbh_[0], hz_); hz_ = MFMA16(ka1_, zbh_[1], hz_); \
    hz_ = MFMA16(ka0_, zbl_[0], hz_); hz_ = MFMA16(ka1_, zbl_[1], hz_); \
    f32x4 hr_ = {0, 0, 0, 0}; \
    _Pragma("unroll") for (int mt = 0; mt < 4; ++mt) { \
      half4v rr_; \
      _Pragma("unroll") for (int j = 0; j < 4; ++j) \
        rr_[j] = (mt < 2) ? rfa##BI[mt * 4 + j] : rfc##BI[(mt - 2) * 4 + j]; \
      hr_ = MFMA16(rr_, th_[mt], hr_); } \
    *(f32x4*)&h2pc[wvc][c * 20 + g * 4] = hz_ + hr_; \
  } while (0)

#define EPILOG(BI, QIV, MV) do { \
    f32x4 h2v_ = *(const f32x4*)&h2pc[0][c * 20 + g * 4]; \
    h2v_ += *(const f32x4*)&h2pc[1][c * 20 + g * 4]; \
    h2v_ += *(const f32x4*)&h2pc[2][c * 20 + g * 4]; \
    h2v_ += *(const f32x4*)&h2pc[3][c * 20 + g * 4]; \
    half4v h2h_, h2l_; \
    _Pragma("unroll") for (int j = 0; j < 4; ++j) { \
      _Float16 h_ = (_Float16)h2v_[j]; \
      h2h_[j] = h_; h2l_[j] = (_Float16)(h2v_[j] - (float)h_); } \
    float qpl_ = 0.f; \
    _Pragma("unroll") for (int mt = 0; mt < 2; ++mt) { \
      half4v pfm_; \
      _Pragma("unroll") for (int j = 0; j < 4; ++j) pfm_[j] = pfx##BI[mt * 4 + j]; \
      f32x4 zz_ = {0, 0, 0, 0}; \
      f32x4 mh_ = MFMA16(pfm_, h2h_, zz_); \
      f32x4 mlv_ = MFMA16(pfm_, h2l_, zz_); \
      f32x4 dd_ = cv##BI[mt] - (mh_ + mlv_); \
      f32x4 mf_ = MV[mt] + dd_; \
      f32x4 zf_ = mf_ + zq##BI[mt]; \
      _Pragma("unroll") for (int r = 0; r < 4; ++r) qpl_ += dd_[r] * dd_[r] * QIV[mt][r]; \
      *(f32x4*)(zf_p + mt * 64) = zf_; \
      zreg[mt] = zf_; \
      half4v zh4_; \
      _Pragma("unroll") for (int r = 0; r < 4; ++r) zh4_[r] = (_Float16)zf_[r]; \
      int row_ = wvc * 4 + mt * 2 + (g >> 1); \
      int base_ = row_ * 128 + (((c + row_) & 15) << 3) + ((g & 1) << 2); \
      *(half4v*)&svhc[base_] = zh4_; \
      f32x4 ms_ = mf_; \
      _Pragma("unroll") for (int r = 0; r < 4; ++r) { \
        float x_ = ms_[r]; \
        x_ += __shfl_xor(x_, 1); x_ += __shfl_xor(x_, 2); \
        x_ += __shfl_xor(x_, 4); x_ += __shfl_xor(x_, 8); \
        ms_[r] = x_ * 0.0625f; } \
      if (c == 0) *(f32x4*)(mf_p + mt * 64) = ms_; \
    } \
    zf_p += 512; mf_p += 512; \
    qpl_ += __shfl_xor(qpl_, 16); \
    qpl_ += __shfl_xor(qpl_, 32); \
    if (g == 0) qppc[BI][wvc * 16 + c] = qpl_; \
  } while (0)

#define PHASE_B(BI, QIV) do { \
    half8v hf_[8]; \
    _Pragma("unroll") for (int kt = 0; kt < 8; ++kt) { \
      int row_ = kt * 4 + g; \
      hf_[kt] = *(const half8v*)&hbc[row_ * 128 + (((c + row_) & 15) << 3)]; } \
    f32x4 a2a_[2], a2b_[2]; \
    _Pragma("unroll") for (int mt = 0; mt < 2; ++mt) { a2a_[mt] = (f32x4){0,0,0,0}; a2b_[mt] = (f32x4){0,0,0,0}; } \
    _Pragma("unroll") for (int kt = 0; kt < 4; ++kt) \
      _Pragma("unroll") for (int mt = 0; mt < 2; ++mt) { \
        a2a_[mt] = MFMA32(w2f[mt][kt], hf_[kt], a2a_[mt]); \
        a2b_[mt] = MFMA32(w2f[mt][kt + 4], hf_[kt + 4], a2b_[mt]); } \
    f32x4 mv_[2]; \
    _Pragma("unroll") for (int mt = 0; mt < 2; ++mt) { \
      mv_[mt] = zreg[mt] + a2a_[mt] + a2b_[mt]; \
      if (wvc < 2) mv_[mt] += ur##BI[mt]; } \
    EPILOG(BI, QIV, mv_); \
  } while (0)

#define KL_FIN(PBI, TPREV) do { \
    if (ct < 16) { \
      float v_ = qppc[PBI][ct] + qppc[PBI][16 + ct] + qppc[PBI][32 + ct] + qppc[PBI][48 + ct]; \
      v_ += __shfl_xor(v_, 1); v_ += __shfl_xor(v_, 2); \
      v_ += __shfl_xor(v_, 4); v_ += __shfl_xor(v_, 8); \
      if (ct == 0) out_kl[(size_t)b * 256 + (size_t)(TPREV)] = 0.03125f * v_ + kv##PBI; \
    } \
  } while (0)

  // ---------------- t = 0 ----------------
  STAGE(0);
  STAGE(1);
  {
    f32x4 mv0[2];
#pragma unroll
    for (int mt = 0; mt < 2; ++mt) {
      mv0[mt] = *(const f32x4*)&m_init[wvc * 32 + mt * 16 + g * 4];
      if (wvc < 2) mv0[mt] += ur0[mt];
    }
    half4v mh0[2], ml0[2];
#pragma unroll
    for (int kt = 0; kt < 2; ++kt)
#pragma unroll
      for (int j = 0; j < 4; ++j) {
        float x = mv0[kt][j];
        _Float16 h = (_Float16)x;
        mh0[kt][j] = h;
        ml0[kt][j] = (_Float16)(x - (float)h);
      }
    half4v ka0_, ka1_;
    KAH(0, 0, ka0_); KAH(0, 1, ka1_);
    f32x4 hz = {0, 0, 0, 0};
    hz = MFMA16(ka0_, mh0[0], hz); hz = MFMA16(ka1_, mh0[1], hz);
    hz = MFMA16(ka0_, ml0[0], hz); hz = MFMA16(ka1_, ml0[1], hz);
    *(f32x4*)&h2pc[wvc][c * 20 + g * 4] = hz;
    BAR();
    EPILOG(0, qiv0, mv0);
    BAR();
  }

  // ---------------- t = 1..254 (pairs) ----------------
  for (int t = 1; t < 255; t += 2) {
    KL_FIN(0, t - 1);
    STAGE(0);
    PHASE_A(1);
    BAR();
    PHASE_B(1, qiv);
    BAR();
    KL_FIN(1, t);
    STAGE(1);
    PHASE_A(0);
    BAR();
    PHASE_B(0, qiv);
    BAR();
  }
  // ---------------- t = 255 ----------------
  KL_FIN(0, 254);
  PHASE_A(1);
  BAR();
  PHASE_B(1, qiv);
  BAR();
  KL_FIN(1, 255);

#undef STAGE
#undef KAH
#undef PHASE_A
#undef EPILOG
#undef PHASE_B
#undef KL_FIN
}

// ============ kscan1: 256 threads, one chain ============
template <bool PK, int ZMODE>
__launch_bounds__(256, 1)
__global__ void kscan1_kernel(const float* __restrict__ ug, const float* __restrict__ Kg,
                              const float* __restrict__ W1, const float* __restrict__ W2,
                              const float* __restrict__ m_init, const float* __restrict__ Qd,
                              const float* __restrict__ Q0d, const _Float16* __restrict__ pfb,
                              const float* __restrict__ cgp, const _Float16* __restrict__ rfb,
                              const _Float16* __restrict__ kab, const float* __restrict__ zpcb,
                              const float* __restrict__ klcp, float* __restrict__ out_zf,
                              float* __restrict__ out_mf, float* __restrict__ out_kl) {
  __shared__ __align__(16) _Float16 svh[2048];
  __shared__ __align__(16) _Float16 hb[4096];
  __shared__ float h2p[4][320];
  __shared__ float qpp[2][64];
  scan_body<PK, ZMODE>(blockIdx.x, threadIdx.x, svh, hb, h2p, qpp,
                       ug, Kg, W1, W2, m_init, Qd, Q0d, pfb, cgp, rfb, kab, zpcb, klcp,
                       out_zf, out_mf, out_kl);
}

// ============ kc3: noise path + R frags; hh and zpc via MFMA (round-16) ============
__global__ void kc3_kernel(const _Float16* __restrict__ kab, const float* __restrict__ epsz,
                           const float* __restrict__ epsw, const float* __restrict__ Qd,
                           const float* __restrict__ Q0d, const float* __restrict__ Ainv,
                           const _Float16* __restrict__ w2h, _Float16* __restrict__ rfb,
                           _Float16* __restrict__ zpch, float* __restrict__ out_zp) {
  int idx = blockIdx.x;
  int t = idx >> 6, b = idx & 63;
  size_t bt = (size_t)b * 256 + t;
  int tid = threadIdx.x;
  const int wv = tid >> 6, ln = tid & 63, g = ln >> 4, c = ln & 15;
  __shared__ _Float16 Ksh[128][18];
  __shared__ float Ai[16][16];
  __shared__ __align__(16) float zp[16][132];
  __shared__ float hh[16][17];
  __shared__ float ww[16][17];
  __shared__ float sq[128];
  __shared__ _Float16 Rh[16][264];
  {
    half8v ko = *(const half8v*)(kab + bt * 2048 + (size_t)tid * 8);
#pragma unroll
    for (int kt = 0; kt < 2; ++kt)
#pragma unroll
      for (int j = 0; j < 4; ++j)
        Ksh[wv * 32 + kt * 16 + g * 4 + j][c] = ko[kt * 4 + j];
  }
  ((float*)Ai)[tid] = Ainv[bt * 256 + tid];
  const float* q = (t == 0) ? Q0d : Qd;
  if (tid < 128) sq[tid] = sqrtf(q[tid]);
  __syncthreads();
  // zp + out_zp (vectorized)
  {
    const f32x4* ez4 = (const f32x4*)(epsz + ((size_t)t * 16 * 64) * 128);
    f32x4* ozp4 = (f32x4*)out_zp;
    for (int i = tid; i < 512; i += 256) {
      int s = i >> 5, l4 = i & 31;
      f32x4 e = ez4[((size_t)s * 64 + b) * 32 + l4];
      f32x4 sv = *(const f32x4*)&sq[l4 * 4];
      f32x4 v = e * sv;
      *(f32x4*)&zp[s][l4 * 4] = v;
      ozp4[(((size_t)s * 64 + b) * 256 + t) * 32 + l4] = v;
    }
  }
  // K column fragments (reused for R and hh)
  half8v kA[4];
#pragma unroll
  for (int kt = 0; kt < 4; ++kt)
#pragma unroll
    for (int j = 0; j < 8; ++j) kA[kt][j] = Ksh[kt * 32 + g * 8 + j][c];
  // R = K^T W2^T via MFMA
  {
#pragma unroll
    for (int i = 0; i < 4; ++i) {
      int tile = wv * 4 + i;
      f32x4 acc = {0, 0, 0, 0};
#pragma unroll
      for (int kt = 0; kt < 4; ++kt) {
        half8v bf = *(const half8v*)&w2h[(size_t)(tile * 16 + c) * 128 + kt * 32 + g * 8];
        acc = MFMA32(kA[kt], bf, acc);
      }
#pragma unroll
      for (int r = 0; r < 4; ++r) Rh[g * 4 + r][tile * 16 + c] = (_Float16)acc[r];
    }
  }
  __syncthreads();
  // rf chunk stores (all threads)
  {
    half8v r0, r1;
#pragma unroll
    for (int mt = 0; mt < 4; ++mt)
#pragma unroll
      for (int j = 0; j < 4; ++j) {
        _Float16 v = Rh[c][wv * 64 + mt * 16 + g * 4 + j];
        if (mt < 2) r0[mt * 4 + j] = v; else r1[(mt - 2) * 4 + j] = v;
      }
    *(half8v*)(rfb + bt * 4096 + (size_t)tid * 16) = r0;
    *(half8v*)(rfb + bt * 4096 + (size_t)tid * 16 + 8) = r1;
  }
  // hh = K^T zp + ew via MFMA (wave 0 only): D[row=g*4+r][col=c] = hh[c][g*4+r]
  if (wv == 0) {
    f32x4 acc = *(const f32x4*)&epsw[(((size_t)t * 16 + c) * 64 + b) * 16 + g * 4];
#pragma unroll
    for (int kt = 0; kt < 4; ++kt) {
      half8v zb;
#pragma unroll
      for (int j = 0; j < 8; ++j) zb[j] = (_Float16)zp[c][kt * 32 + g * 8 + j];
      acc = MFMA32(kA[kt], zb, acc);
    }
#pragma unroll
    for (int r = 0; r < 4; ++r) hh[c][g * 4 + r] = acc[r];
  }
  __syncthreads();
  // ww = Ainv hh (scalar, cheap)
  {
    int s = tid >> 4, r = tid & 15;
    float acc = 0.f;
#pragma unroll
    for (int j = 0; j < 16; ++j) acc += Ai[r][j] * hh[s][j];
    ww[s][r] = acc;
  }
  __syncthreads();
  // zpc = zp - K ww via MFMA16; D layout lands exactly in zpch fragment order
  {
    half8v zo;
#pragma unroll
    for (int mt = 0; mt < 2; ++mt) {
      half4v ka4, wb;
#pragma unroll
      for (int j = 0; j < 4; ++j) {
        ka4[j] = Ksh[(wv * 2 + mt) * 16 + c][g * 4 + j];
        wb[j] = (_Float16)ww[c][g * 4 + j];
      }
      f32x4 zzero = {0, 0, 0, 0};
      f32x4 pre = MFMA16(ka4, wb, zzero);
#pragma unroll
      for (int j = 0; j < 4; ++j) {
        int l = wv * 32 + mt * 16 + g * 4 + j;
        zo[mt * 4 + j] = (_Float16)(zp[c][l] - pre[j]);
      }
    }
    *(half8v*)(zpch + bt * 2048 + (size_t)tid * 8) = zo;
  }
}

// ============ kprep1 (round-12 proven): A, chol, Ainv, klc, pf, c', kab ============
__global__ void kprep1_kernel(const float* __restrict__ Kg, const float* __restrict__ kg,
                              const float* __restrict__ ug, const float* __restrict__ Qd,
                              const float* __restrict__ Q0d, float* __restrict__ Ainv,
                              float* __restrict__ klc, _Float16* __restrict__ pfb,
                              float* __restrict__ cgp, _Float16* __restrict__ kab) {
  int tid = threadIdx.x;
  int wv = tid >> 6, ln = tid & 63;
  size_t bt = (size_t)blockIdx.x * 4 + wv;
  int t = (int)(bt & 255);
  __shared__ __align__(16) float Ks[4][128][20];
  __shared__ float qs[4][128];
  __shared__ float vvs[4][128];
  __shared__ float Asm[4][16][20];
  __shared__ float LiL[4][16][20];
  __shared__ float AiS[4][16][20];
  __shared__ float yps[4][4][16];
  __shared__ float yvs[4][16];
  const f32x4* kp4 = (const f32x4*)(Kg + bt * 2048);
  for (int i = ln; i < 512; i += 64) {
    f32x4 v = kp4[i];
    *(f32x4*)&Ks[wv][i >> 2][(i & 3) * 4] = v;
  }
  for (int l = ln; l < 128; l += 64) {
    float q = (t == 0) ? Q0d[l] : Qd[l];
    qs[wv][l] = q;
    float v = Qd[l] * kg[bt * 128 + l];
    if (t > 0 && l < 64) v += ug[bt * 64 + l];
    vvs[wv][l] = v;
  }
  __syncthreads();
  if (kab) {
    int gg = ln >> 4, cc2 = ln & 15;
#pragma unroll
    for (int q = 0; q < 4; ++q) {
      half8v ko;
#pragma unroll
      for (int kt = 0; kt < 2; ++kt)
#pragma unroll
        for (int j = 0; j < 4; ++j)
          ko[kt * 4 + j] = (_Float16)Ks[wv][q * 32 + kt * 16 + gg * 4 + j][cc2];
      *(half8v*)(kab + bt * 2048 + (size_t)(q * 64 + ln) * 8) = ko;
    }
  }
  {
    int r = ln & 15, c0 = (ln >> 4) << 2;
    float a0 = 0, a1 = 0, a2 = 0, a3 = 0;
    for (int l = 0; l < 128; ++l) {
      float kq = Ks[wv][l][r] * qs[wv][l];
      const float* row = &Ks[wv][l][c0];
      a0 += kq * row[0]; a1 += kq * row[1]; a2 += kq * row[2]; a3 += kq * row[3];
    }
    Asm[wv][r][c0 + 0] = a0 + ((r == c0 + 0) ? 1.f : 0.f);
    Asm[wv][r][c0 + 1] = a1 + ((r == c0 + 1) ? 1.f : 0.f);
    Asm[wv][r][c0 + 2] = a2 + ((r == c0 + 2) ? 1.f : 0.f);
    Asm[wv][r][c0 + 3] = a3 + ((r == c0 + 3) ? 1.f : 0.f);
  }
  {
    int r = ln & 15, seg = ln >> 4;
    float s = 0.f;
    for (int l = seg * 32; l < seg * 32 + 32; ++l) s += Ks[wv][l][r] * vvs[wv][l];
    yps[wv][seg][r] = s;
  }
  __syncthreads();
  if (ln < 16) {
    int i = ln;
    float ar[16], Lr[16];
#pragma unroll
    for (int j = 0; j < 16; ++j) ar[j] = Asm[wv][i][j];
    float ld = 0.f;
#pragma unroll
    for (int j = 0; j < 16; ++j) {
      float ajj = __shfl(ar[j], j, 64);
      float d = sqrtf(ajj);
      ld += __logf(d);
      float li = ar[j] / d;
      li = (i >= j) ? li : 0.f;
      Lr[j] = li;
#pragma unroll
      for (int k2 = j; k2 < 16; ++k2) {
        float lk = __shfl(li, k2, 64);
        ar[k2] -= li * lk;
      }
    }
    int cc = i;
    float Lic[16];
#pragma unroll
    for (int ii = 0; ii < 16; ++ii) {
      float s = (ii == cc) ? 1.f : 0.f;
#pragma unroll
      for (int p = 0; p < 16; ++p) {
        if (p < ii) {
          float Lip = __shfl(Lr[p], ii, 64);
          s -= Lip * Lic[p];
        }
      }
      float dii = __shfl(Lr[ii], ii, 64);
      float v = s / dii;
      Lic[ii] = (ii >= cc) ? v : 0.f;
    }
    float tr = 0.f;
#pragma unroll
    for (int ii = 0; ii < 16; ++ii) { tr += Lic[ii] * Lic[ii]; LiL[wv][cc][ii] = Lic[ii]; }
    tr += __shfl_xor(tr, 1); tr += __shfl_xor(tr, 2);
    tr += __shfl_xor(tr, 4); tr += __shfl_xor(tr, 8);
    if (cc == 0) klc[bt] = 0.5f * (tr - 16.f + 2.f * ld);
    yvs[wv][cc] = yps[wv][0][cc] + yps[wv][1][cc] + yps[wv][2][cc] + yps[wv][3][cc];
  }
  __syncthreads();
  {
    int r = ln & 15, c0 = (ln >> 4) << 2;
    float a0 = 0, a1 = 0, a2 = 0, a3 = 0;
    for (int ii = 0; ii < 16; ++ii) {
      float lir = LiL[wv][r][ii];
      a0 += lir * LiL[wv][c0 + 0][ii];
      a1 += lir * LiL[wv][c0 + 1][ii];
      a2 += lir * LiL[wv][c0 + 2][ii];
      a3 += lir * LiL[wv][c0 + 3][ii];
    }
    AiS[wv][r][c0 + 0] = a0; AiS[wv][r][c0 + 1] = a1;
    AiS[wv][r][c0 + 2] = a2; AiS[wv][r][c0 + 3] = a3;
    f32x4 av = {a0, a1, a2, a3};
    *(f32x4*)&Ainv[bt * 256 + r * 16 + c0] = av;
  }
  __syncthreads();
  {
#pragma unroll
    for (int li = 0; li < 2; ++li) {
      int l = ln * 2 + li;
      f32x4 acc0 = {0,0,0,0}, acc1v = {0,0,0,0}, acc2v = {0,0,0,0}, acc3v = {0,0,0,0};
      for (int j = 0; j < 16; ++j) {
        float kj = Ks[wv][l][j];
        acc0  += kj * *(const f32x4*)&AiS[wv][j][0];
        acc1v += kj * *(const f32x4*)&AiS[wv][j][4];
        acc2v += kj * *(const f32x4*)&AiS[wv][j][8];
        acc3v += kj * *(const f32x4*)&AiS[wv][j][12];
      }
      float ql = qs[wv][l];
      float cp = ql * kg[bt * 128 + l];
      float pv[16];
#pragma unroll
      for (int e = 0; e < 4; ++e) {
        pv[e] = ql * acc0[e]; pv[4 + e] = ql * acc1v[e];
        pv[8 + e] = ql * acc2v[e]; pv[12 + e] = ql * acc3v[e];
      }
#pragma unroll
      for (int r = 0; r < 16; ++r) cp -= pv[r] * yvs[wv][r];
      cgp[bt * 128 + l] = cp;
#pragma unroll
      for (int r = 0; r < 16; ++r) Ks[wv][l][r] = pv[r];
    }
  }
  __syncthreads();
  {
    int gp = ln >> 4, cp = ln & 15;
#pragma unroll
    for (int ci = 0; ci < 4; ++ci) {
      half8v o;
#pragma unroll
      for (int mt = 0; mt < 2; ++mt)
#pragma unroll
        for (int j = 0; j < 4; ++j)
          o[mt * 4 + j] = (_Float16)Ks[wv][ci * 32 + mt * 16 + cp][gp * 4 + j];
      *(half8v*)(pfb + bt * 2048 + (size_t)(ci * 64 + ln) * 8) = o;
    }
  }
}

// ============ round-7 small-ws fallback kernels ============
__global__ void kprepR_kernel(const float* __restrict__ Kg, const _Float16* __restrict__ w2h,
                              _Float16* __restrict__ rfb, _Float16* __restrict__ kab) {
  int tid = threadIdx.x;
  int wv = tid >> 6, ln = tid & 63;
  int g = ln >> 4, c = ln & 15;
  __shared__ _Float16 Kh[128][20];
  __shared__ _Float16 Rh[16][264];
  for (int it = 0; it < 4; ++it) {
    size_t bt = (size_t)blockIdx.x * 4 + it;
    const float* kp = Kg + bt * 2048;
    for (int i = tid; i < 2048; i += 256) Kh[i >> 4][i & 15] = (_Float16)kp[i];
    __syncthreads();
    half8v kA[4];
#pragma unroll
    for (int kt = 0; kt < 4; ++kt)
#pragma unroll
      for (int j = 0; j < 8; ++j) kA[kt][j] = Kh[kt * 32 + g * 8 + j][c];
#pragma unroll
    for (int i = 0; i < 4; ++i) {
      int tile = wv * 4 + i;
      f32x4 acc = {0, 0, 0, 0};
#pragma unroll
      for (int kt = 0; kt < 4; ++kt) {
        half8v bf = *(const half8v*)&w2h[(size_t)(tile * 16 + c) * 128 + kt * 32 + g * 8];
        acc = MFMA32(kA[kt], bf, acc);
      }
#pragma unroll
      for (int r = 0; r < 4; ++r) Rh[g * 4 + r][tile * 16 + c] = (_Float16)acc[r];
    }
    __syncthreads();
    half8v r0, r1;
#pragma unroll
    for (int mt = 0; mt < 4; ++mt)
#pragma unroll
      for (int j = 0; j < 4; ++j) {
        _Float16 v = Rh[c][wv * 64 + mt * 16 + g * 4 + j];
        if (mt < 2) r0[mt * 4 + j] = v; else r1[(mt - 2) * 4 + j] = v;
      }
    *(half8v*)(rfb + bt * 4096 + (size_t)tid * 16) = r0;
    *(half8v*)(rfb + bt * 4096 + (size_t)tid * 16 + 8) = r1;
    if (kab) {
      half8v ko;
#pragma unroll
      for (int kt = 0; kt < 2; ++kt)
#pragma unroll
        for (int j = 0; j < 4; ++j) ko[kt * 4 + j] = Kh[wv * 32 + kt * 16 + g * 4 + j][c];
      *(half8v*)(kab + bt * 2048 + (size_t)tid * 8) = ko;
    }
    __syncthreads();
  }
}

__global__ void kc_kernel(const float* __restrict__ Kg, const float* __restrict__ epsz,
                          const float* __restrict__ epsw, const float* __restrict__ Qd,
                          const float* __restrict__ Q0d, const float* __restrict__ Ainv,
                          float* __restrict__ out_zf, float* __restrict__ out_zp,
                          float* __restrict__ zpcb, int zw, int wzp) {
  int idx = blockIdx.x;
  int t = idx >> 6, b = idx & 63;
  int bt = b * 256 + t;
  __shared__ float Ks[128][16];
  __shared__ float Ai[16][16];
  __shared__ float zp[16][129];
  __shared__ float hh[16][17];
  __shared__ float ww[16][17];
  __shared__ float sq[128];
  const float* kp = Kg + (size_t)bt * 2048;
  for (int i = threadIdx.x; i < 2048; i += 256) ((float*)Ks)[i] = kp[i];
  ((float*)Ai)[threadIdx.x] = Ainv[(size_t)bt * 256 + threadIdx.x];
  const float* q = (t == 0) ? Q0d : Qd;
  if (threadIdx.x < 128) sq[threadIdx.x] = sqrtf(q[threadIdx.x]);
  __syncthreads();
  for (int i = threadIdx.x; i < 2048; i += 256) {
    int s = i >> 7, l = i & 127;
    float v = sq[l] * epsz[(((size_t)t * 16 + s) * 64 + b) * 128 + l];
    zp[s][l] = v;
    if (wzp) out_zp[(((size_t)s * 64 + b) * 256 + t) * 128 + l] = v;
  }
  __syncthreads();
  {
    int s = threadIdx.x >> 4, r = threadIdx.x & 15;
    float acc = epsw[(((size_t)t * 16 + s) * 64 + b) * 16 + r];
    for (int l = 0; l < 128; ++l) acc += Ks[l][r] * zp[s][l];
    hh[s][r] = acc;
  }
  __syncthreads();
  {
    int s = threadIdx.x >> 4, r = threadIdx.x & 15;
    float acc = 0.f;
    for (int j = 0; j < 16; ++j) acc += Ai[r][j] * hh[s][j];
    ww[s][r] = acc;
  }
  __syncthreads();
  for (int i = threadIdx.x; i < 2048; i += 256) {
    int s = i >> 7, l = i & 127;
    float acc = 0.f;
    for (int r = 0; r < 16; ++r) acc += Ks[l][r] * ww[s][r];
    float v = zp[s][l] - acc;
    if (zw) zpcb[(size_t)bt * 2048 + i] = v;
    else out_zf[(((size_t)s * 64 + b) * 256 + t) * 128 + l] = v;
  }
}

__global__ void kzp_kernel(const float* __restrict__ epsz, const float* __restrict__ Qd,
                           const float* __restrict__ Q0d, float* __restrict__ out_zp) {
  for (size_t i = (size_t)blockIdx.x * blockDim.x + threadIdx.x; i < (size_t)33554432;
       i += (size_t)gridDim.x * blockDim.x) {
    int l = (int)(i & 127);
    int t = (int)((i >> 7) & 255);
    int sb = (int)(i >> 15);
    int s = sb >> 6, b = sb & 63;
    float q = (t == 0) ? Q0d[l] : Qd[l];
    out_zp[i] = sqrtf(q) * epsz[(((size_t)t * 16 + s) * 64 + b) * 128 + l];
  }
}

extern "C" void kernel_launch(void* const* d_in, const int* in_sizes, int n_in,
                              void* d_out, int out_size, void* d_ws, size_t ws_size,
                              hipStream_t stream) {
  (void)in_sizes; (void)n_in; (void)out_size;
  const float* u   = (const float*)d_in[0];
  const float* kk  = (const float*)d_in[1];
  const float* Kg  = (const float*)d_in[2];
  const float* epz = (const float*)d_in[3];
  const float* epw = (const float*)d_in[4];
  const float* W1  = (const float*)d_in[5];
  const float* W2  = (const float*)d_in[6];
  const float* mi  = (const float*)d_in[7];
  const float* Qd  = (const float*)d_in[8];
  const float* Q0d = (const float*)d_in[9];

  float* out_zf = (float*)d_out;
  float* out_mf = out_zf + (size_t)33554432;
  float* out_zp = out_mf + (size_t)2097152;
  float* out_kl = out_zp + (size_t)33554432;

  char* ws = (char*)d_ws;

  // ---- primary plan (zpc f16) ----
  const size_t F_klc  = 0;                 // 65,536
  const size_t F_cgp  = 65536;             // 8,388,608
  const size_t F_pfb  = 8454144;           // 67,108,864
  const size_t F_w2h  = 75563008;          // 65,536
  const size_t F_kab  = 75628544;          // 67,108,864
  const size_t F_rfb  = 142737408;         // 134,217,728
  const size_t F_zpc  = 276955136;         // 67,108,864 (f16)
  const size_t F_ainv = 344064000;         // 16,777,216
  const size_t F_END  = 360841216;

  if (ws_size >= F_END) {
    float*    klc  = (float*)(ws + F_klc);
    float*    cgp  = (float*)(ws + F_cgp);
    _Float16* pfb  = (_Float16*)(ws + F_pfb);
    _Float16* w2h  = (_Float16*)(ws + F_w2h);
    _Float16* kab  = (_Float16*)(ws + F_kab);
    _Float16* rfb  = (_Float16*)(ws + F_rfb);
    _Float16* zpch = (_Float16*)(ws + F_zpc);
    float*    Ainv = (float*)(ws + F_ainv);
    kw2_kernel<<<128, 256, 0, stream>>>(W2, w2h);
    kprep1_kernel<<<4096, 256, 0, stream>>>(Kg, kk, u, Qd, Q0d, Ainv, klc, pfb, cgp, kab);
    kc3_kernel<<<16384, 256, 0, stream>>>(kab, epz, epw, Qd, Q0d, Ainv, w2h,
                                          rfb, zpch, out_zp);
    kscan1_kernel<true, 2><<<64, 256, 0, stream>>>(u, Kg, W1, W2, mi, Qd, Q0d, pfb,
                                                   cgp, rfb, kab, (const float*)zpch, klc,
                                                   out_zf, out_mf, out_kl);
    return;
  }

  // ---- small-ws fallback (round-7 path) ----
  size_t off = 0;
  auto take = [&](size_t n) { char* p = ws + off; off += n; return p; };
  float*    Ainv = (float*)take(16777216);
  float*    klc  = (float*)take(65536);
  float*    cgp  = (float*)take(8388608);
  _Float16* pfb  = (_Float16*)take(67108864);
  _Float16* w2h  = (_Float16*)take(65536);
  bool zw = ws_size >= off + 134217728;
  float* zpcb = zw ? (float*)take(134217728) : nullptr;
  bool pk = zw && (ws_size >= off + 67108864);
  _Float16* kab = pk ? (_Float16*)take(67108864) : nullptr;
  bool rfws = ws_size >= off + 134217728;
  _Float16* rfb = rfws ? (_Float16*)take(134217728) : (_Float16*)out_zp;
  int wzp = rfws ? 1 : 0;

  kw2_kernel<<<128, 256, 0, stream>>>(W2, w2h);
  kprep1_kernel<<<4096, 256, 0, stream>>>(Kg, kk, u, Qd, Q0d, Ainv, klc, pfb, cgp, nullptr);
  kprepR_kernel<<<4096, 256, 0, stream>>>(Kg, w2h, rfb, kab);
  kc_kernel<<<16384, 256, 0, stream>>>(Kg, epz, epw, Qd, Q0d, Ainv, out_zf, out_zp,
                                       zpcb, zw ? 1 : 0, wzp);
  if (pk)
    kscan1_kernel<true, 1><<<64, 256, 0, stream>>>(u, Kg, W1, W2, mi, Qd, Q0d, pfb, cgp, rfb, kab, zpcb, klc, out_zf, out_mf, out_kl);
  else if (zw)
    kscan1_kernel<false, 1><<<64, 256, 0, stream>>>(u, Kg, W1, W2, mi, Qd, Q0d, pfb, cgp, rfb, kab, zpcb, klc, out_zf, out_mf, out_kl);
  else
    kscan1_kernel<false, 0><<<64, 256, 0, stream>>>(u, Kg, W1, W2, mi, Qd, Q0d, pfb, cgp, rfb, kab, zpcb, klc, out_zf, out_mf, out_kl);
  if (!rfws) kzp_kernel<<<2048, 256, 0, stream>>>(epz, Qd, Q0d, out_zp);
}

// Round 17
// 944.371 us; speedup vs baseline: 2.2533x; 1.0245x over previous
//
#include <hip/hip_runtime.h>
#include <cstddef>

typedef _Float16 half8v __attribute__((ext_vector_type(8)));
typedef _Float16 half4v __attribute__((ext_vector_type(4)));
typedef float f32x4 __attribute__((ext_vector_type(4)));

#define MFMA32(A, B, C) __builtin_amdgcn_mfma_f32_16x16x32_f16(A, B, C, 0, 0, 0)
#define MFMA16(A, B, C) __builtin_amdgcn_mfma_f32_16x16x16f16(A, B, C, 0, 0, 0)

// ============ kw2: W2 -> f16 copy ============
__global__ void kw2_kernel(const float* __restrict__ W2, _Float16* __restrict__ w2h) {
  int i = blockIdx.x * 256 + threadIdx.x;
  w2h[i] = (_Float16)W2[i];
}

#define BAR() asm volatile("s_waitcnt lgkmcnt(0)\n\ts_barrier" ::: "memory")

// ============ scan body (round-7 proven) ============
// ZMODE: 0 = zpc aliased in out_zf (f32), 1 = zpcb f32, 2 = zpcb f16 fragments
template <bool PK, int ZMODE>
__device__ __forceinline__ void scan_body(
    const int b, const int ct,
    _Float16* __restrict__ svhc, _Float16* __restrict__ hbc,
    float (*__restrict__ h2pc)[320], float (*__restrict__ qppc)[64],
    const float* __restrict__ ug, const float* __restrict__ Kg,
    const float* __restrict__ W1, const float* __restrict__ W2,
    const float* __restrict__ m_init, const float* __restrict__ Qd,
    const float* __restrict__ Q0d, const _Float16* __restrict__ pfb,
    const float* __restrict__ cgp, const _Float16* __restrict__ rfb,
    const _Float16* __restrict__ kab, const float* __restrict__ zpcb,
    const float* __restrict__ klcp, float* __restrict__ out_zf,
    float* __restrict__ out_mf, float* __restrict__ out_kl) {
  const int wvc = ct >> 6;
  const int ln = ct & 63;
  const int g = ln >> 4;
  const int c = ln & 15;

  half8v w1f[4][4];
#pragma unroll
  for (int mt = 0; mt < 4; ++mt)
#pragma unroll
    for (int kt = 0; kt < 4; ++kt) {
      half8v v;
#pragma unroll
      for (int j = 0; j < 8; ++j)
        v[j] = (_Float16)W1[(size_t)(kt * 32 + g * 8 + j) * 256 + (wvc * 64 + mt * 16 + c)];
      w1f[mt][kt] = v;
    }
  half8v w2f[2][8];
#pragma unroll
  for (int mt = 0; mt < 2; ++mt)
#pragma unroll
    for (int kt = 0; kt < 8; ++kt) {
      half8v v;
#pragma unroll
      for (int j = 0; j < 8; ++j)
        v[j] = (_Float16)W2[(size_t)(kt * 32 + g * 8 + j) * 128 + (wvc * 32 + mt * 16 + c)];
      w2f[mt][kt] = v;
    }

  f32x4 qiv[2], qiv0[2];
#pragma unroll
  for (int mt = 0; mt < 2; ++mt) {
    f32x4 q = *(const f32x4*)&Qd[wvc * 32 + mt * 16 + g * 4];
    f32x4 q0 = *(const f32x4*)&Q0d[wvc * 32 + mt * 16 + g * 4];
#pragma unroll
    for (int r = 0; r < 4; ++r) { qiv[mt][r] = 1.f / q[r]; qiv0[mt][r] = 1.f / q0[r]; }
  }

  f32x4 zreg[2];

  half8v pfx0, pfx1, kax0 = {}, kax1 = {}, rfa0, rfa1, rfc0, rfc1;
  float kf0[8], kf1[8];
  f32x4 zq0[2], zq1[2], cv0[2], cv1[2];
  f32x4 ur0[2] = {}, ur1[2] = {};
  float kv0 = 0.f, kv1 = 0.f;

  const char* pf_p = (const char*)pfb + (size_t)b * 256 * 4096 + (size_t)ct * 16;
  const char* ka_p = PK ? (const char*)kab + (size_t)b * 256 * 4096 + (size_t)ct * 16
                        : (const char*)pfb;
  const char* K_p = (const char*)Kg + (size_t)b * 256 * 8192 + (size_t)((wvc * 32 + g * 4) * 16 + c) * 4;
  const char* rf_p = (const char*)rfb + (size_t)b * 256 * 8192 + (size_t)ct * 32;
  const char* zq_p;
  size_t zq_str;
  if constexpr (ZMODE == 2) {
    zq_p = (const char*)zpcb + (size_t)b * 256 * 4096 + (size_t)ct * 16;
    zq_str = 4096;
  } else if constexpr (ZMODE == 1) {
    zq_p = (const char*)zpcb + (size_t)b * 256 * 8192 + (size_t)(c * 128 + wvc * 32 + g * 4) * 4;
    zq_str = 8192;
  } else {
    zq_p = (const char*)out_zf + ((((size_t)c * 64 + b) * 256) * 128 + wvc * 32 + g * 4) * 4;
    zq_str = 512;
  }
  const char* cv_p = (const char*)cgp + (size_t)b * 256 * 512 + (size_t)(wvc * 32 + g * 4) * 4;
  const char* ur_p = (const char*)ug + (size_t)b * 256 * 256 + (size_t)(wvc * 32 + g * 4) * 4;
  const char* kl_p = (const char*)klcp + (size_t)b * 256 * 4;
  char* zf_p = (char*)out_zf + ((((size_t)c * 64 + b) * 256) * 128 + wvc * 32 + g * 4) * 4;
  char* mf_p = (char*)out_mf + ((size_t)b * 256 * 128 + wvc * 32 + g * 4) * 4;

#define STAGE(BI) do { \
    pfx##BI = *(const half8v*)pf_p; pf_p += 4096; \
    if constexpr (PK) { kax##BI = *(const half8v*)ka_p; ka_p += 4096; } \
    else { _Pragma("unroll") for (int kt_ = 0; kt_ < 2; ++kt_) \
             _Pragma("unroll") for (int j_ = 0; j_ < 4; ++j_) \
               kf##BI[kt_ * 4 + j_] = *(const float*)(K_p + kt_ * 1024 + j_ * 64); \
           K_p += 8192; } \
    rfa##BI = *(const half8v*)rf_p; rfc##BI = *(const half8v*)(rf_p + 16); rf_p += 8192; \
    if constexpr (ZMODE == 2) { \
      half8v zo_ = *(const half8v*)zq_p; \
      _Pragma("unroll") for (int j_ = 0; j_ < 4; ++j_) { \
        zq##BI[0][j_] = (float)zo_[j_]; zq##BI[1][j_] = (float)zo_[4 + j_]; } \
    } else { \
      zq##BI[0] = *(const f32x4*)zq_p; zq##BI[1] = *(const f32x4*)(zq_p + 64); \
    } \
    zq_p += zq_str; \
    cv##BI[0] = *(const f32x4*)cv_p; cv##BI[1] = *(const f32x4*)(cv_p + 64); cv_p += 512; \
    if (wvc < 2) { ur##BI[0] = *(const f32x4*)ur_p; ur##BI[1] = *(const f32x4*)(ur_p + 64); } \
    ur_p += 256; \
    kv##BI = *(const float*)kl_p; kl_p += 4; \
  } while (0)

#define KAH(BI, KT, DST) do { \
    if constexpr (PK) { _Pragma("unroll") for (int j_ = 0; j_ < 4; ++j_) DST[j_] = kax##BI[(KT) * 4 + j_]; } \
    else { _Pragma("unroll") for (int j_ = 0; j_ < 4; ++j_) DST[j_] = (_Float16)kf##BI[(KT) * 4 + j_]; } \
  } while (0)

#define PHASE_A(BI) do { \
    half4v zbh_[2], zbl_[2]; \
    _Pragma("unroll") for (int kt = 0; kt < 2; ++kt) \
      _Pragma("unroll") for (int j = 0; j < 4; ++j) { \
        float x_ = zreg[kt][j]; _Float16 h_ = (_Float16)x_; \
        zbh_[kt][j] = h_; zbl_[kt][j] = (_Float16)(x_ - (float)h_); } \
    half8v zh8_[4]; \
    _Pragma("unroll") for (int kt = 0; kt < 4; ++kt) { \
      int row_ = kt * 4 + g; \
      int idx_ = row_ * 128 + (((c + row_) & 15) << 3); \
      zh8_[kt] = *(const half8v*)&svhc[idx_]; } \
    f32x4 a1h_[4]; \
    _Pragma("unroll") for (int mt = 0; mt < 4; ++mt) a1h_[mt] = (f32x4){0,0,0,0}; \
    _Pragma("unroll") for (int kt = 0; kt < 4; ++kt) \
      _Pragma("unroll") for (int mt = 0; mt < 4; ++mt) \
        a1h_[mt] = MFMA32(w1f[mt][kt], zh8_[kt], a1h_[mt]); \
    half4v th_[4]; \
    _Pragma("unroll") for (int mt = 0; mt < 4; ++mt) { \
      _Pragma("unroll") for (int r = 0; r < 4; ++r) { \
        float x_ = a1h_[mt][r]; \
        float e_ = __expf(2.f * x_); \
        th_[mt][r] = (_Float16)(1.f - 2.f / (e_ + 1.f)); } \
      int row_ = wvc * 8 + mt * 2 + (g >> 1); \
      *(half4v*)&hbc[row_ * 128 + (((c + row_) & 15) << 3) + ((g & 1) << 2)] = th_[mt]; } \
    half4v ka0_, ka1_; KAH(BI, 0, ka0_); KAH(BI, 1, ka1_); \
    f32x4 hz_ = {0, 0, 0, 0}; \
    hz_ = MFMA16(ka0_, zbh_[0], hz_); hz_ = MFMA16(ka1_, zbh_[1], hz_); \
    hz_ = MFMA16(ka0_, zbl_[0], hz_); hz_ = MFMA16(ka1_, zbl_[1], hz_); \
    f32x4 hr_ = {0, 0, 0, 0}; \
    _Pragma("unroll") for (int mt = 0; mt < 4; ++mt) { \
      half4v rr_; \
      _Pragma("unroll") for (int j = 0; j < 4; ++j) \
        rr_[j] = (mt < 2) ? rfa##BI[mt * 4 + j] : rfc##BI[(mt - 2) * 4 + j]; \
      hr_ = MFMA16(rr_, th_[mt], hr_); } \
    *(f32x4*)&h2pc[wvc][c * 20 + g * 4] = hz_ + hr_; \
  } while (0)

#define EPILOG(BI, QIV, MV) do { \
    f32x4 h2v_ = *(const f32x4*)&h2pc[0][c * 20 + g * 4]; \
    h2v_ += *(const f32x4*)&h2pc[1][c * 20 + g * 4]; \
    h2v_ += *(const f32x4*)&h2pc[2][c * 20 + g * 4]; \
    h2v_ += *(const f32x4*)&h2pc[3][c * 20 + g * 4]; \
    half4v h2h_, h2l_; \
    _Pragma("unroll") for (int j = 0; j < 4; ++j) { \
      _Float16 h_ = (_Float16)h2v_[j]; \
      h2h_[j] = h_; h2l_[j] = (_Float16)(h2v_[j] - (float)h_); } \
    float qpl_ = 0.f; \
    _Pragma("unroll") for (int mt = 0; mt < 2; ++mt) { \
      half4v pfm_; \
      _Pragma("unroll") for (int j = 0; j < 4; ++j) pfm_[j] = pfx##BI[mt * 4 + j]; \
      f32x4 zz_ = {0, 0, 0, 0}; \
      f32x4 mh_ = MFMA16(pfm_, h2h_, zz_); \
      f32x4 mlv_ = MFMA16(pfm_, h2l_, zz_); \
      f32x4 dd_ = cv##BI[mt] - (mh_ + mlv_); \
      f32x4 mf_ = MV[mt] + dd_; \
      f32x4 zf_ = mf_ + zq##BI[mt]; \
      _Pragma("unroll") for (int r = 0; r < 4; ++r) qpl_ += dd_[r] * dd_[r] * QIV[mt][r]; \
      *(f32x4*)(zf_p + mt * 64) = zf_; \
      zreg[mt] = zf_; \
      half4v zh4_; \
      _Pragma("unroll") for (int r = 0; r < 4; ++r) zh4_[r] = (_Float16)zf_[r]; \
      int row_ = wvc * 4 + mt * 2 + (g >> 1); \
      int base_ = row_ * 128 + (((c + row_) & 15) << 3) + ((g & 1) << 2); \
      *(half4v*)&svhc[base_] = zh4_; \
      f32x4 ms_ = mf_; \
      _Pragma("unroll") for (int r = 0; r < 4; ++r) { \
        float x_ = ms_[r]; \
        x_ += __shfl_xor(x_, 1); x_ += __shfl_xor(x_, 2); \
        x_ += __shfl_xor(x_, 4); x_ += __shfl_xor(x_, 8); \
        ms_[r] = x_ * 0.0625f; } \
      if (c == 0) *(f32x4*)(mf_p + mt * 64) = ms_; \
    } \
    zf_p += 512; mf_p += 512; \
    qpl_ += __shfl_xor(qpl_, 16); \
    qpl_ += __shfl_xor(qpl_, 32); \
    if (g == 0) qppc[BI][wvc * 16 + c] = qpl_; \
  } while (0)

#define PHASE_B(BI, QIV) do { \
    half8v hf_[8]; \
    _Pragma("unroll") for (int kt = 0; kt < 8; ++kt) { \
      int row_ = kt * 4 + g; \
      hf_[kt] = *(const half8v*)&hbc[row_ * 128 + (((c + row_) & 15) << 3)]; } \
    f32x4 a2a_[2], a2b_[2]; \
    _Pragma("unroll") for (int mt = 0; mt < 2; ++mt) { a2a_[mt] = (f32x4){0,0,0,0}; a2b_[mt] = (f32x4){0,0,0,0}; } \
    _Pragma("unroll") for (int kt = 0; kt < 4; ++kt) \
      _Pragma("unroll") for (int mt = 0; mt < 2; ++mt) { \
        a2a_[mt] = MFMA32(w2f[mt][kt], hf_[kt], a2a_[mt]); \
        a2b_[mt] = MFMA32(w2f[mt][kt + 4], hf_[kt + 4], a2b_[mt]); } \
    f32x4 mv_[2]; \
    _Pragma("unroll") for (int mt = 0; mt < 2; ++mt) { \
      mv_[mt] = zreg[mt] + a2a_[mt] + a2b_[mt]; \
      if (wvc < 2) mv_[mt] += ur##BI[mt]; } \
    EPILOG(BI, QIV, mv_); \
  } while (0)

#define KL_FIN(PBI, TPREV) do { \
    if (ct < 16) { \
      float v_ = qppc[PBI][ct] + qppc[PBI][16 + ct] + qppc[PBI][32 + ct] + qppc[PBI][48 + ct]; \
      v_ += __shfl_xor(v_, 1); v_ += __shfl_xor(v_, 2); \
      v_ += __shfl_xor(v_, 4); v_ += __shfl_xor(v_, 8); \
      if (ct == 0) out_kl[(size_t)b * 256 + (size_t)(TPREV)] = 0.03125f * v_ + kv##PBI; \
    } \
  } while (0)

  // ---------------- t = 0 ----------------
  STAGE(0);
  STAGE(1);
  {
    f32x4 mv0[2];
#pragma unroll
    for (int mt = 0; mt < 2; ++mt) {
      mv0[mt] = *(const f32x4*)&m_init[wvc * 32 + mt * 16 + g * 4];
      if (wvc < 2) mv0[mt] += ur0[mt];
    }
    half4v mh0[2], ml0[2];
#pragma unroll
    for (int kt = 0; kt < 2; ++kt)
#pragma unroll
      for (int j = 0; j < 4; ++j) {
        float x = mv0[kt][j];
        _Float16 h = (_Float16)x;
        mh0[kt][j] = h;
        ml0[kt][j] = (_Float16)(x - (float)h);
      }
    half4v ka0_, ka1_;
    KAH(0, 0, ka0_); KAH(0, 1, ka1_);
    f32x4 hz = {0, 0, 0, 0};
    hz = MFMA16(ka0_, mh0[0], hz); hz = MFMA16(ka1_, mh0[1], hz);
    hz = MFMA16(ka0_, ml0[0], hz); hz = MFMA16(ka1_, ml0[1], hz);
    *(f32x4*)&h2pc[wvc][c * 20 + g * 4] = hz;
    BAR();
    EPILOG(0, qiv0, mv0);
    BAR();
  }

  // ---------------- t = 1..254 (pairs) ----------------
  for (int t = 1; t < 255; t += 2) {
    KL_FIN(0, t - 1);
    STAGE(0);
    PHASE_A(1);
    BAR();
    PHASE_B(1, qiv);
    BAR();
    KL_FIN(1, t);
    STAGE(1);
    PHASE_A(0);
    BAR();
    PHASE_B(0, qiv);
    BAR();
  }
  // ---------------- t = 255 ----------------
  KL_FIN(0, 254);
  PHASE_A(1);
  BAR();
  PHASE_B(1, qiv);
  BAR();
  KL_FIN(1, 255);

#undef STAGE
#undef KAH
#undef PHASE_A
#undef EPILOG
#undef PHASE_B
#undef KL_FIN
}

// ============ kscan1: 256 threads, one chain ============
template <bool PK, int ZMODE>
__launch_bounds__(256, 1)
__global__ void kscan1_kernel(const float* __restrict__ ug, const float* __restrict__ Kg,
                              const float* __restrict__ W1, const float* __restrict__ W2,
                              const float* __restrict__ m_init, const float* __restrict__ Qd,
                              const float* __restrict__ Q0d, const _Float16* __restrict__ pfb,
                              const float* __restrict__ cgp, const _Float16* __restrict__ rfb,
                              const _Float16* __restrict__ kab, const float* __restrict__ zpcb,
                              const float* __restrict__ klcp, float* __restrict__ out_zf,
                              float* __restrict__ out_mf, float* __restrict__ out_kl) {
  __shared__ __align__(16) _Float16 svh[2048];
  __shared__ __align__(16) _Float16 hb[4096];
  __shared__ float h2p[4][320];
  __shared__ float qpp[2][64];
  scan_body<PK, ZMODE>(blockIdx.x, threadIdx.x, svh, hb, h2p, qpp,
                       ug, Kg, W1, W2, m_init, Qd, Q0d, pfb, cgp, rfb, kab, zpcb, klcp,
                       out_zf, out_mf, out_kl);
}

// ============ kc3: noise path + R frags; hh and zpc via MFMA (round-16 proven) ============
__global__ void kc3_kernel(const _Float16* __restrict__ kab, const float* __restrict__ epsz,
                           const float* __restrict__ epsw, const float* __restrict__ Qd,
                           const float* __restrict__ Q0d, const float* __restrict__ Ainv,
                           const _Float16* __restrict__ w2h, _Float16* __restrict__ rfb,
                           _Float16* __restrict__ zpch, float* __restrict__ out_zp) {
  int idx = blockIdx.x;
  int t = idx >> 6, b = idx & 63;
  size_t bt = (size_t)b * 256 + t;
  int tid = threadIdx.x;
  const int wv = tid >> 6, ln = tid & 63, g = ln >> 4, c = ln & 15;
  __shared__ _Float16 Ksh[128][18];
  __shared__ float Ai[16][16];
  __shared__ __align__(16) float zp[16][132];
  __shared__ float hh[16][17];
  __shared__ float ww[16][17];
  __shared__ float sq[128];
  __shared__ _Float16 Rh[16][264];
  {
    half8v ko = *(const half8v*)(kab + bt * 2048 + (size_t)tid * 8);
#pragma unroll
    for (int kt = 0; kt < 2; ++kt)
#pragma unroll
      for (int j = 0; j < 4; ++j)
        Ksh[wv * 32 + kt * 16 + g * 4 + j][c] = ko[kt * 4 + j];
  }
  ((float*)Ai)[tid] = Ainv[bt * 256 + tid];
  const float* q = (t == 0) ? Q0d : Qd;
  if (tid < 128) sq[tid] = sqrtf(q[tid]);
  __syncthreads();
  // zp + out_zp (vectorized)
  {
    const f32x4* ez4 = (const f32x4*)(epsz + ((size_t)t * 16 * 64) * 128);
    f32x4* ozp4 = (f32x4*)out_zp;
    for (int i = tid; i < 512; i += 256) {
      int s = i >> 5, l4 = i & 31;
      f32x4 e = ez4[((size_t)s * 64 + b) * 32 + l4];
      f32x4 sv = *(const f32x4*)&sq[l4 * 4];
      f32x4 v = e * sv;
      *(f32x4*)&zp[s][l4 * 4] = v;
      ozp4[(((size_t)s * 64 + b) * 256 + t) * 32 + l4] = v;
    }
  }
  // K column fragments (reused for R and hh)
  half8v kA[4];
#pragma unroll
  for (int kt = 0; kt < 4; ++kt)
#pragma unroll
    for (int j = 0; j < 8; ++j) kA[kt][j] = Ksh[kt * 32 + g * 8 + j][c];
  // R = K^T W2^T via MFMA
  {
#pragma unroll
    for (int i = 0; i < 4; ++i) {
      int tile = wv * 4 + i;
      f32x4 acc = {0, 0, 0, 0};
#pragma unroll
      for (int kt = 0; kt < 4; ++kt) {
        half8v bf = *(const half8v*)&w2h[(size_t)(tile * 16 + c) * 128 + kt * 32 + g * 8];
        acc = MFMA32(kA[kt], bf, acc);
      }
#pragma unroll
      for (int r = 0; r < 4; ++r) Rh[g * 4 + r][tile * 16 + c] = (_Float16)acc[r];
    }
  }
  __syncthreads();
  // rf chunk stores (all threads)
  {
    half8v r0, r1;
#pragma unroll
    for (int mt = 0; mt < 4; ++mt)
#pragma unroll
      for (int j = 0; j < 4; ++j) {
        _Float16 v = Rh[c][wv * 64 + mt * 16 + g * 4 + j];
        if (mt < 2) r0[mt * 4 + j] = v; else r1[(mt - 2) * 4 + j] = v;
      }
    *(half8v*)(rfb + bt * 4096 + (size_t)tid * 16) = r0;
    *(half8v*)(rfb + bt * 4096 + (size_t)tid * 16 + 8) = r1;
  }
  // hh = K^T zp + ew via MFMA (wave 0 only): D[row=g*4+r][col=c] = hh[c][g*4+r]
  if (wv == 0) {
    f32x4 acc = *(const f32x4*)&epsw[(((size_t)t * 16 + c) * 64 + b) * 16 + g * 4];
#pragma unroll
    for (int kt = 0; kt < 4; ++kt) {
      half8v zb;
#pragma unroll
      for (int j = 0; j < 8; ++j) zb[j] = (_Float16)zp[c][kt * 32 + g * 8 + j];
      acc = MFMA32(kA[kt], zb, acc);
    }
#pragma unroll
    for (int r = 0; r < 4; ++r) hh[c][g * 4 + r] = acc[r];
  }
  __syncthreads();
  // ww = Ainv hh (scalar, cheap)
  {
    int s = tid >> 4, r = tid & 15;
    float acc = 0.f;
#pragma unroll
    for (int j = 0; j < 16; ++j) acc += Ai[r][j] * hh[s][j];
    ww[s][r] = acc;
  }
  __syncthreads();
  // zpc = zp - K ww via MFMA16; D layout lands exactly in zpch fragment order
  {
    half8v zo;
#pragma unroll
    for (int mt = 0; mt < 2; ++mt) {
      half4v ka4, wb;
#pragma unroll
      for (int j = 0; j < 4; ++j) {
        ka4[j] = Ksh[(wv * 2 + mt) * 16 + c][g * 4 + j];
        wb[j] = (_Float16)ww[c][g * 4 + j];
      }
      f32x4 zzero = {0, 0, 0, 0};
      f32x4 pre = MFMA16(ka4, wb, zzero);
#pragma unroll
      for (int j = 0; j < 4; ++j) {
        int l = wv * 32 + mt * 16 + g * 4 + j;
        zo[mt * 4 + j] = (_Float16)(zp[c][l] - pre[j]);
      }
    }
    *(half8v*)(zpch + bt * 2048 + (size_t)tid * 8) = zo;
  }
}

// ============ kprep1: A + P via MFMA (round-17); chol/Ainv/klc/pf/c'/kab as before ============
__global__ void kprep1_kernel(const float* __restrict__ Kg, const float* __restrict__ kg,
                              const float* __restrict__ ug, const float* __restrict__ Qd,
                              const float* __restrict__ Q0d, float* __restrict__ Ainv,
                              float* __restrict__ klc, _Float16* __restrict__ pfb,
                              float* __restrict__ cgp, _Float16* __restrict__ kab) {
  int tid = threadIdx.x;
  int wv = tid >> 6, ln = tid & 63;
  size_t bt = (size_t)blockIdx.x * 4 + wv;
  int t = (int)(bt & 255);
  const int g = ln >> 4, c = ln & 15;
  __shared__ __align__(16) float Ks[4][128][20];
  __shared__ float qs[4][128];
  __shared__ float vvs[4][128];
  __shared__ float Asm[4][16][20];
  __shared__ float LiL[4][16][20];
  __shared__ float AiS[4][16][20];
  __shared__ float yps[4][4][16];
  __shared__ float yvs[4][16];
  const f32x4* kp4 = (const f32x4*)(Kg + bt * 2048);
  for (int i = ln; i < 512; i += 64) {
    f32x4 v = kp4[i];
    *(f32x4*)&Ks[wv][i >> 2][(i & 3) * 4] = v;
  }
  for (int l = ln; l < 128; l += 64) {
    float q = (t == 0) ? Q0d[l] : Qd[l];
    qs[wv][l] = q;
    float v = Qd[l] * kg[bt * 128 + l];
    if (t > 0 && l < 64) v += ug[bt * 64 + l];
    vvs[wv][l] = v;
  }
  __syncthreads();
  if (kab) {
    int gg = ln >> 4, cc2 = ln & 15;
#pragma unroll
    for (int q = 0; q < 4; ++q) {
      half8v ko;
#pragma unroll
      for (int kt = 0; kt < 2; ++kt)
#pragma unroll
        for (int j = 0; j < 4; ++j)
          ko[kt * 4 + j] = (_Float16)Ks[wv][q * 32 + kt * 16 + gg * 4 + j][cc2];
      *(half8v*)(kab + bt * 2048 + (size_t)(q * 64 + ln) * 8) = ko;
    }
  }
  // ---- A = I + K^T Q K via MFMA32 (hi/lo on both operands, lo*lo dropped) ----
  {
    f32x4 acc = {0, 0, 0, 0};
#pragma unroll
    for (int kt = 0; kt < 4; ++kt) {
      half8v kh, kl2, bh, bl2;
#pragma unroll
      for (int j = 0; j < 8; ++j) {
        int l = kt * 32 + g * 8 + j;
        float kv = Ks[wv][l][c];
        _Float16 h = (_Float16)kv;
        kh[j] = h;
        kl2[j] = (_Float16)(kv - (float)h);
        float bv = qs[wv][l] * kv;
        _Float16 bhh = (_Float16)bv;
        bh[j] = bhh;
        bl2[j] = (_Float16)(bv - (float)bhh);
      }
      acc = MFMA32(kh, bh, acc);
      acc = MFMA32(kh, bl2, acc);
      acc = MFMA32(kl2, bh, acc);
    }
#pragma unroll
    for (int r = 0; r < 4; ++r) {
      int row = g * 4 + r;
      Asm[wv][row][c] = acc[r] + ((row == c) ? 1.f : 0.f);
    }
  }
  {
    int r = ln & 15, seg = ln >> 4;
    float s = 0.f;
    for (int l = seg * 32; l < seg * 32 + 32; ++l) s += Ks[wv][l][r] * vvs[wv][l];
    yps[wv][seg][r] = s;
  }
  __syncthreads();
  if (ln < 16) {
    int i = ln;
    float ar[16], Lr[16];
#pragma unroll
    for (int j = 0; j < 16; ++j) ar[j] = Asm[wv][i][j];
    float ld = 0.f;
#pragma unroll
    for (int j = 0; j < 16; ++j) {
      float ajj = __shfl(ar[j], j, 64);
      float d = sqrtf(ajj);
      ld += __logf(d);
      float li = ar[j] / d;
      li = (i >= j) ? li : 0.f;
      Lr[j] = li;
#pragma unroll
      for (int k2 = j; k2 < 16; ++k2) {
        float lk = __shfl(li, k2, 64);
        ar[k2] -= li * lk;
      }
    }
    int cc = i;
    float Lic[16];
#pragma unroll
    for (int ii = 0; ii < 16; ++ii) {
      float s = (ii == cc) ? 1.f : 0.f;
#pragma unroll
      for (int p = 0; p < 16; ++p) {
        if (p < ii) {
          float Lip = __shfl(Lr[p], ii, 64);
          s -= Lip * Lic[p];
        }
      }
      float dii = __shfl(Lr[ii], ii, 64);
      float v = s / dii;
      Lic[ii] = (ii >= cc) ? v : 0.f;
    }
    float tr = 0.f;
#pragma unroll
    for (int ii = 0; ii < 16; ++ii) { tr += Lic[ii] * Lic[ii]; LiL[wv][cc][ii] = Lic[ii]; }
    tr += __shfl_xor(tr, 1); tr += __shfl_xor(tr, 2);
    tr += __shfl_xor(tr, 4); tr += __shfl_xor(tr, 8);
    if (cc == 0) klc[bt] = 0.5f * (tr - 16.f + 2.f * ld);
    yvs[wv][cc] = yps[wv][0][cc] + yps[wv][1][cc] + yps[wv][2][cc] + yps[wv][3][cc];
  }
  __syncthreads();
  {
    int r = ln & 15, c0 = (ln >> 4) << 2;
    float a0 = 0, a1 = 0, a2 = 0, a3 = 0;
    for (int ii = 0; ii < 16; ++ii) {
      float lir = LiL[wv][r][ii];
      a0 += lir * LiL[wv][c0 + 0][ii];
      a1 += lir * LiL[wv][c0 + 1][ii];
      a2 += lir * LiL[wv][c0 + 2][ii];
      a3 += lir * LiL[wv][c0 + 3][ii];
    }
    AiS[wv][r][c0 + 0] = a0; AiS[wv][r][c0 + 1] = a1;
    AiS[wv][r][c0 + 2] = a2; AiS[wv][r][c0 + 3] = a3;
    f32x4 av = {a0, a1, a2, a3};
    *(f32x4*)&Ainv[bt * 256 + r * 16 + c0] = av;
  }
  __syncthreads();
  // ---- P = q*(K Ainv) via MFMA16 (Ainv hi/lo); write P into Ks slab ----
  {
    half4v wbh, wbl;
#pragma unroll
    for (int j = 0; j < 4; ++j) {
      float a = AiS[wv][g * 4 + j][c];
      _Float16 h = (_Float16)a;
      wbh[j] = h;
      wbl[j] = (_Float16)(a - (float)h);
    }
    f32x4 pacc[8];
#pragma unroll
    for (int rt = 0; rt < 8; ++rt) {
      half4v ka4;
#pragma unroll
      for (int j = 0; j < 4; ++j) ka4[j] = (_Float16)Ks[wv][rt * 16 + c][g * 4 + j];
      f32x4 z4 = {0, 0, 0, 0};
      f32x4 acc = MFMA16(ka4, wbh, z4);
      acc = MFMA16(ka4, wbl, acc);
      pacc[rt] = acc;
    }
#pragma unroll
    for (int rt = 0; rt < 8; ++rt)
#pragma unroll
      for (int r = 0; r < 4; ++r) {
        int l = rt * 16 + g * 4 + r;
        Ks[wv][l][c] = qs[wv][l] * pacc[rt][r];
      }
  }
  __syncthreads();
  // ---- c' = q*k - P.y2 ----
  {
#pragma unroll
    for (int li = 0; li < 2; ++li) {
      int l = ln * 2 + li;
      float cp = qs[wv][l] * kg[bt * 128 + l];
#pragma unroll
      for (int r = 0; r < 16; ++r) cp -= Ks[wv][l][r] * yvs[wv][r];
      cgp[bt * 128 + l] = cp;
    }
  }
  // ---- pf gather ----
  {
    int gp = ln >> 4, cp = ln & 15;
#pragma unroll
    for (int ci = 0; ci < 4; ++ci) {
      half8v o;
#pragma unroll
      for (int mt = 0; mt < 2; ++mt)
#pragma unroll
        for (int j = 0; j < 4; ++j)
          o[mt * 4 + j] = (_Float16)Ks[wv][ci * 32 + mt * 16 + cp][gp * 4 + j];
      *(half8v*)(pfb + bt * 2048 + (size_t)(ci * 64 + ln) * 8) = o;
    }
  }
}

// ============ round-7 small-ws fallback kernels ============
__global__ void kprepR_kernel(const float* __restrict__ Kg, const _Float16* __restrict__ w2h,
                              _Float16* __restrict__ rfb, _Float16* __restrict__ kab) {
  int tid = threadIdx.x;
  int wv = tid >> 6, ln = tid & 63;
  int g = ln >> 4, c = ln & 15;
  __shared__ _Float16 Kh[128][20];
  __shared__ _Float16 Rh[16][264];
  for (int it = 0; it < 4; ++it) {
    size_t bt = (size_t)blockIdx.x * 4 + it;
    const float* kp = Kg + bt * 2048;
    for (int i = tid; i < 2048; i += 256) Kh[i >> 4][i & 15] = (_Float16)kp[i];
    __syncthreads();
    half8v kA[4];
#pragma unroll
    for (int kt = 0; kt < 4; ++kt)
#pragma unroll
      for (int j = 0; j < 8; ++j) kA[kt][j] = Kh[kt * 32 + g * 8 + j][c];
#pragma unroll
    for (int i = 0; i < 4; ++i) {
      int tile = wv * 4 + i;
      f32x4 acc = {0, 0, 0, 0};
#pragma unroll
      for (int kt = 0; kt < 4; ++kt) {
        half8v bf = *(const half8v*)&w2h[(size_t)(tile * 16 + c) * 128 + kt * 32 + g * 8];
        acc = MFMA32(kA[kt], bf, acc);
      }
#pragma unroll
      for (int r = 0; r < 4; ++r) Rh[g * 4 + r][tile * 16 + c] = (_Float16)acc[r];
    }
    __syncthreads();
    half8v r0, r1;
#pragma unroll
    for (int mt = 0; mt < 4; ++mt)
#pragma unroll
      for (int j = 0; j < 4; ++j) {
        _Float16 v = Rh[c][wv * 64 + mt * 16 + g * 4 + j];
        if (mt < 2) r0[mt * 4 + j] = v; else r1[(mt - 2) * 4 + j] = v;
      }
    *(half8v*)(rfb + bt * 4096 + (size_t)tid * 16) = r0;
    *(half8v*)(rfb + bt * 4096 + (size_t)tid * 16 + 8) = r1;
    if (kab) {
      half8v ko;
#pragma unroll
      for (int kt = 0; kt < 2; ++kt)
#pragma unroll
        for (int j = 0; j < 4; ++j) ko[kt * 4 + j] = Kh[wv * 32 + kt * 16 + g * 4 + j][c];
      *(half8v*)(kab + bt * 2048 + (size_t)tid * 8) = ko;
    }
    __syncthreads();
  }
}

__global__ void kc_kernel(const float* __restrict__ Kg, const float* __restrict__ epsz,
                          const float* __restrict__ epsw, const float* __restrict__ Qd,
                          const float* __restrict__ Q0d, const float* __restrict__ Ainv,
                          float* __restrict__ out_zf, float* __restrict__ out_zp,
                          float* __restrict__ zpcb, int zw, int wzp) {
  int idx = blockIdx.x;
  int t = idx >> 6, b = idx & 63;
  int bt = b * 256 + t;
  __shared__ float Ks[128][16];
  __shared__ float Ai[16][16];
  __shared__ float zp[16][129];
  __shared__ float hh[16][17];
  __shared__ float ww[16][17];
  __shared__ float sq[128];
  const float* kp = Kg + (size_t)bt * 2048;
  for (int i = threadIdx.x; i < 2048; i += 256) ((float*)Ks)[i] = kp[i];
  ((float*)Ai)[threadIdx.x] = Ainv[(size_t)bt * 256 + threadIdx.x];
  const float* q = (t == 0) ? Q0d : Qd;
  if (threadIdx.x < 128) sq[threadIdx.x] = sqrtf(q[threadIdx.x]);
  __syncthreads();
  for (int i = threadIdx.x; i < 2048; i += 256) {
    int s = i >> 7, l = i & 127;
    float v = sq[l] * epsz[(((size_t)t * 16 + s) * 64 + b) * 128 + l];
    zp[s][l] = v;
    if (wzp) out_zp[(((size_t)s * 64 + b) * 256 + t) * 128 + l] = v;
  }
  __syncthreads();
  {
    int s = threadIdx.x >> 4, r = threadIdx.x & 15;
    float acc = epsw[(((size_t)t * 16 + s) * 64 + b) * 16 + r];
    for (int l = 0; l < 128; ++l) acc += Ks[l][r] * zp[s][l];
    hh[s][r] = acc;
  }
  __syncthreads();
  {
    int s = threadIdx.x >> 4, r = threadIdx.x & 15;
    float acc = 0.f;
    for (int j = 0; j < 16; ++j) acc += Ai[r][j] * hh[s][j];
    ww[s][r] = acc;
  }
  __syncthreads();
  for (int i = threadIdx.x; i < 2048; i += 256) {
    int s = i >> 7, l = i & 127;
    float acc = 0.f;
    for (int r = 0; r < 16; ++r) acc += Ks[l][r] * ww[s][r];
    float v = zp[s][l] - acc;
    if (zw) zpcb[(size_t)bt * 2048 + i] = v;
    else out_zf[(((size_t)s * 64 + b) * 256 + t) * 128 + l] = v;
  }
}

__global__ void kzp_kernel(const float* __restrict__ epsz, const float* __restrict__ Qd,
                           const float* __restrict__ Q0d, float* __restrict__ out_zp) {
  for (size_t i = (size_t)blockIdx.x * blockDim.x + threadIdx.x; i < (size_t)33554432;
       i += (size_t)gridDim.x * blockDim.x) {
    int l = (int)(i & 127);
    int t = (int)((i >> 7) & 255);
    int sb = (int)(i >> 15);
    int s = sb >> 6, b = sb & 63;
    float q = (t == 0) ? Q0d[l] : Qd[l];
    out_zp[i] = sqrtf(q) * epsz[(((size_t)t * 16 + s) * 64 + b) * 128 + l];
  }
}

extern "C" void kernel_launch(void* const* d_in, const int* in_sizes, int n_in,
                              void* d_out, int out_size, void* d_ws, size_t ws_size,
                              hipStream_t stream) {
  (void)in_sizes; (void)n_in; (void)out_size;
  const float* u   = (const float*)d_in[0];
  const float* kk  = (const float*)d_in[1];
  const float* Kg  = (const float*)d_in[2];
  const float* epz = (const float*)d_in[3];
  const float* epw = (const float*)d_in[4];
  const float* W1  = (const float*)d_in[5];
  const float* W2  = (const float*)d_in[6];
  const float* mi  = (const float*)d_in[7];
  const float* Qd  = (const float*)d_in[8];
  const float* Q0d = (const float*)d_in[9];

  float* out_zf = (float*)d_out;
  float* out_mf = out_zf + (size_t)33554432;
  float* out_zp = out_mf + (size_t)2097152;
  float* out_kl = out_zp + (size_t)33554432;

  char* ws = (char*)d_ws;

  // ---- primary plan (zpc f16) ----
  const size_t F_klc  = 0;                 // 65,536
  const size_t F_cgp  = 65536;             // 8,388,608
  const size_t F_pfb  = 8454144;           // 67,108,864
  const size_t F_w2h  = 75563008;          // 65,536
  const size_t F_kab  = 75628544;          // 67,108,864
  const size_t F_rfb  = 142737408;         // 134,217,728
  const size_t F_zpc  = 276955136;         // 67,108,864 (f16)
  const size_t F_ainv = 344064000;         // 16,777,216
  const size_t F_END  = 360841216;

  if (ws_size >= F_END) {
    float*    klc  = (float*)(ws + F_klc);
    float*    cgp  = (float*)(ws + F_cgp);
    _Float16* pfb  = (_Float16*)(ws + F_pfb);
    _Float16* w2h  = (_Float16*)(ws + F_w2h);
    _Float16* kab  = (_Float16*)(ws + F_kab);
    _Float16* rfb  = (_Float16*)(ws + F_rfb);
    _Float16* zpch = (_Float16*)(ws + F_zpc);
    float*    Ainv = (float*)(ws + F_ainv);
    kw2_kernel<<<128, 256, 0, stream>>>(W2, w2h);
    kprep1_kernel<<<4096, 256, 0, stream>>>(Kg, kk, u, Qd, Q0d, Ainv, klc, pfb, cgp, kab);
    kc3_kernel<<<16384, 256, 0, stream>>>(kab, epz, epw, Qd, Q0d, Ainv, w2h,
                                          rfb, zpch, out_zp);
    kscan1_kernel<true, 2><<<64, 256, 0, stream>>>(u, Kg, W1, W2, mi, Qd, Q0d, pfb,
                                                   cgp, rfb, kab, (const float*)zpch, klc,
                                                   out_zf, out_mf, out_kl);
    return;
  }

  // ---- small-ws fallback (round-7 path) ----
  size_t off = 0;
  auto take = [&](size_t n) { char* p = ws + off; off += n; return p; };
  float*    Ainv = (float*)take(16777216);
  float*    klc  = (float*)take(65536);
  float*    cgp  = (float*)take(8388608);
  _Float16* pfb  = (_Float16*)take(67108864);
  _Float16* w2h  = (_Float16*)take(65536);
  bool zw = ws_size >= off + 134217728;
  float* zpcb = zw ? (float*)take(134217728) : nullptr;
  bool pk = zw && (ws_size >= off + 67108864);
  _Float16* kab = pk ? (_Float16*)take(67108864) : nullptr;
  bool rfws = ws_size >= off + 134217728;
  _Float16* rfb = rfws ? (_Float16*)take(134217728) : (_Float16*)out_zp;
  int wzp = rfws ? 1 : 0;

  kw2_kernel<<<128, 256, 0, stream>>>(W2, w2h);
  kprep1_kernel<<<4096, 256, 0, stream>>>(Kg, kk, u, Qd, Q0d, Ainv, klc, pfb, cgp, nullptr);
  kprepR_kernel<<<4096, 256, 0, stream>>>(Kg, w2h, rfb, kab);
  kc_kernel<<<16384, 256, 0, stream>>>(Kg, epz, epw, Qd, Q0d, Ainv, out_zf, out_zp,
                                       zpcb, zw ? 1 : 0, wzp);
  if (pk)
    kscan1_kernel<true, 1><<<64, 256, 0, stream>>>(u, Kg, W1, W2, mi, Qd, Q0d, pfb, cgp, rfb, kab, zpcb, klc, out_zf, out_mf, out_kl);
  else if (zw)
    kscan1_kernel<false, 1><<<64, 256, 0, stream>>>(u, Kg, W1, W2, mi, Qd, Q0d, pfb, cgp, rfb, kab, zpcb, klc, out_zf, out_mf, out_kl);
  else
    kscan1_kernel<false, 0><<<64, 256, 0, stream>>>(u, Kg, W1, W2, mi, Qd, Q0d, pfb, cgp, rfb, kab, zpcb, klc, out_zf, out_mf, out_kl);
  if (!rfws) kzp_kernel<<<2048, 256, 0, stream>>>(epz, Qd, Q0d, out_zp);
}